// Round 5
// baseline (455.680 us; speedup 1.0000x reference)
//
#include <hip/hip_runtime.h>

typedef unsigned short u16;
typedef unsigned int u32;
typedef __bf16 bf16x8 __attribute__((ext_vector_type(8)));
typedef float f32x4 __attribute__((ext_vector_type(4)));

#define NTOK 4097
#define MTOK 513
#define MPAD 544     // 34*16 (xln row padding)
#define KPAD 640     // K/V padded
#define NPAD_Q 4224  // 33*128
#define ROWS_X 16512 // 129*128

#define NBLK 448       // 1.75 blocks/CU avg; 64KB LDS -> 2/CU capacity = 512 >= 448 (co-residency margin)
#define MAGIC 0x1234ABCDu

__device__ __forceinline__ u16 f2bf(float f) {  // RNE (outputs)
  u32 u = __builtin_bit_cast(u32, f);
  u = u + 0x7FFFu + ((u >> 16) & 1u);
  return (u16)(u >> 16);
}
__device__ __forceinline__ u16 f2bf_fast(float f) {  // round-half-up (internal P)
  u32 u = __builtin_bit_cast(u32, f);
  return (u16)((u + 0x8000u) >> 16);
}

// async global->LDS DMA, 16B per lane; LDS dest = wave-uniform base + lane*16
__device__ __forceinline__ void gld16(const u16* g, u16* l) {
  __builtin_amdgcn_global_load_lds((const __attribute__((address_space(1))) u32*)g,
                                   (__attribute__((address_space(3))) u32*)l, 16, 0, 0);
}

#define NQW  147456
#define NKVW 294912
#define NPW  147456
#define GQW  (NQW / 8)
#define GKVW (NKVW / 8)
#define GPW  (NPW / 8)
#define GW   (GQW + GKVW + GPW)  // 73,728 = 288*256 exactly
#define P0_SRLN (4 * MTOK)       // 2052
#define P0_N    (P0_SRLN + 288)
#define P1_N    489              // 387 q-tiles + 102 kv-tiles
#define P2_N    1056             // 32*33 attn tiles
#define P3_N    387              // 129*3 out-proj tiles

// ---------- grid barrier: monotonic counter, device-scope; stale state passes (never hangs) ----------
__device__ __forceinline__ void gbar(u32* c) {
  __syncthreads();
  if (threadIdx.x == 0) {
    __threadfence();  // my block's global writes visible before signaling
    atomicAdd(c, 1u); // device scope by default on CDNA
    while (__hip_atomic_load(c, __ATOMIC_ACQUIRE, __HIP_MEMORY_SCOPE_AGENT) < NBLK)
      __builtin_amdgcn_s_sleep(2);
  }
  __syncthreads();
}

// ---------------- per-channel sr-conv value (verbatim math) ----------------
__device__ __forceinline__ float srln_val(const float* __restrict__ x, const float* __restrict__ srw,
                                          const float* __restrict__ srb, int b, int m, int c) {
  if (m == 0) return x[(b * NTOK) * 384 + c];
  int mo = m - 1;
  int oz = mo >> 6, oy = (mo >> 3) & 7, ox = mo & 7;
  float acc = srb[c];
#pragma unroll
  for (int dz = 0; dz < 2; dz++)
#pragma unroll
    for (int dy = 0; dy < 2; dy++)
#pragma unroll
      for (int dx = 0; dx < 2; dx++) {
        int tok = 1 + ((2 * oz + dz) * 256 + (2 * oy + dy) * 16 + (2 * ox + dx));
        acc += x[(b * NTOK + tok) * 384 + c] * srw[c * 8 + dz * 4 + dy * 2 + dx];
      }
  return acc;
}

// ---------------- GEMM core (R2-proven dbuf body, verbatim; modes 1,2) ----------------
__device__ __forceinline__ void gemm_core(u16* aLds, u16* bLds,
                                          const u16* A, const u16* __restrict__ W,
                                          int mode, size_t rbase, int c0,
                                          u16* __restrict__ o1, u16* __restrict__ o2,
                                          float* __restrict__ of, const float* __restrict__ bias) {
  int tid = threadIdx.x, w = tid >> 6, lane = tid & 63, q4 = lane >> 4, c16 = lane & 15;
  int wr = w >> 1, wc = w & 1;
  int x7 = c16 & 7;

  auto stageAB = [&](int kc, int buf) {
#pragma unroll
    for (int i = 0; i < 4; i++) {
      int s = (w * 4 + i) * 64 + lane;
      int row = s >> 3, chp = s & 7;
      int ch = chp ^ (row & 7);
      gld16(A + (rbase + row) * 384 + kc * 64 + ch * 8, &aLds[buf * 8192 + (w * 4 + i) * 512]);
    }
#pragma unroll
    for (int i = 0; i < 4; i++) {
      int s = (w * 4 + i) * 64 + lane;
      int row = s >> 3, chp = s & 7;
      int ch = chp ^ (row & 7);
      gld16(W + (size_t)(c0 + row) * 384 + kc * 64 + ch * 8, &bLds[buf * 8192 + (w * 4 + i) * 512]);
    }
  };
  stageAB(0, 0);
  __syncthreads();

  f32x4 acc[4][4];
#pragma unroll
  for (int mt = 0; mt < 4; mt++)
#pragma unroll
    for (int nt = 0; nt < 4; nt++) acc[mt][nt] = (f32x4){0, 0, 0, 0};

  for (int c = 0; c < 6; c++) {
    int cb = c & 1, nb = cb ^ 1;
    if (c < 5) stageAB(c + 1, nb);  // async; drains at this iter's end barrier
#pragma unroll
    for (int ks = 0; ks < 2; ks++) {
      bf16x8 af[4], bf[4];
#pragma unroll
      for (int mt = 0; mt < 4; mt++)
        af[mt] = *(const bf16x8*)(&aLds[cb * 8192 + (wr * 64 + mt * 16 + c16) * 64 + ((ks * 4 + q4) ^ x7) * 8]);
#pragma unroll
      for (int nt = 0; nt < 4; nt++)
        bf[nt] = *(const bf16x8*)(&bLds[cb * 8192 + (wc * 64 + nt * 16 + c16) * 64 + ((ks * 4 + q4) ^ x7) * 8]);
#pragma unroll
      for (int mt = 0; mt < 4; mt++)
#pragma unroll
        for (int nt = 0; nt < 4; nt++)
          acc[mt][nt] = __builtin_amdgcn_mfma_f32_16x16x32_bf16(af[mt], bf[nt], acc[mt][nt], 0, 0, 0);
    }
    __syncthreads();
  }

#pragma unroll
  for (int mt = 0; mt < 4; mt++)
#pragma unroll
    for (int nt = 0; nt < 4; nt++) {
      int col = c0 + wc * 64 + nt * 16 + c16;
#pragma unroll
      for (int r = 0; r < 4; r++) {
        int R = (int)rbase + wr * 64 + mt * 16 + q4 * 4 + r;
        float val = acc[mt][nt][r];
        if (mode == 1) {
          int b = R / MPAD;
          int m = R - b * MPAD;
          if (col < 384) {
            int h = col / 48, d = col - h * 48;
            o1[((size_t)(b * 8 + h) * KPAD + m) * 64 + d] = f2bf(val);
          } else {
            int c2 = col - 384;
            int h = c2 / 48, d = c2 - h * 48;
            o2[((size_t)(b * 8 + h) * 48 + d) * KPAD + m] = f2bf(val);
          }
        } else {
          if (R < 4 * NTOK) of[(size_t)R * 384 + col] = val + bias[col];
        }
      }
    }
}

// ---------------- GEMM core, f32-A variant (R2-proven dbuf body, verbatim) ----------------
__device__ __forceinline__ void gemm_core_f32A(u16* aLds, u16* bLds,
                                               const float* __restrict__ X, const u16* __restrict__ W,
                                               size_t rbase, int c0, u16* __restrict__ o1) {
  int tid = threadIdx.x, w = tid >> 6, lane = tid & 63, q4 = lane >> 4, c16 = lane & 15;
  int wr = w >> 1, wc = w & 1;
  int x7 = c16 & 7;

  float4 ra[2][2];
  auto loadA2 = [&](int kc, int half) {
#pragma unroll
    for (int i = 0; i < 2; i++) {
      int idx2 = half * 2 + i;
      int s = (w * 4 + idx2) * 64 + lane;
      int row = s >> 3, chp = s & 7;
      int ch = chp ^ (row & 7);
      int ar = (int)rbase + row;
      if (ar > 16387) ar = 16387;  // clamp pad rows (outputs discarded: b>=4)
      const float* pa = X + (size_t)ar * 384 + kc * 64 + ch * 8;
      ra[i][0] = *(const float4*)pa;
      ra[i][1] = *(const float4*)(pa + 4);
    }
  };
  auto writeA2 = [&](int buf, int half) {
#pragma unroll
    for (int i = 0; i < 2; i++) {
      int idx2 = half * 2 + i;
      uint4 oa;
      u16* p = (u16*)&oa;
      p[0] = f2bf(ra[i][0].x); p[1] = f2bf(ra[i][0].y);
      p[2] = f2bf(ra[i][0].z); p[3] = f2bf(ra[i][0].w);
      p[4] = f2bf(ra[i][1].x); p[5] = f2bf(ra[i][1].y);
      p[6] = f2bf(ra[i][1].z); p[7] = f2bf(ra[i][1].w);
      *(uint4*)(&aLds[buf * 8192 + (w * 4 + idx2) * 512 + lane * 8]) = oa;
    }
  };
  auto stageB = [&](int kc, int buf) {
#pragma unroll
    for (int i = 0; i < 4; i++) {
      int s = (w * 4 + i) * 64 + lane;
      int row = s >> 3, chp = s & 7;
      int ch = chp ^ (row & 7);
      gld16(W + (size_t)(c0 + row) * 384 + kc * 64 + ch * 8, &bLds[buf * 8192 + (w * 4 + i) * 512]);
    }
  };

  loadA2(0, 0);
  stageB(0, 0);
  writeA2(0, 0);
  loadA2(0, 1);
  writeA2(0, 1);
  __syncthreads();

  f32x4 acc[4][4];
#pragma unroll
  for (int mt = 0; mt < 4; mt++)
#pragma unroll
    for (int nt = 0; nt < 4; nt++) acc[mt][nt] = (f32x4){0, 0, 0, 0};

  for (int c = 0; c < 6; c++) {
    int cb = c & 1, nb = cb ^ 1;
    if (c < 5) { loadA2(c + 1, 0); stageB(c + 1, nb); }
    // ks = 0
    {
      bf16x8 af[4], bf[4];
#pragma unroll
      for (int mt = 0; mt < 4; mt++)
        af[mt] = *(const bf16x8*)(&aLds[cb * 8192 + (wr * 64 + mt * 16 + c16) * 64 + ((0 + q4) ^ x7) * 8]);
#pragma unroll
      for (int nt = 0; nt < 4; nt++)
        bf[nt] = *(const bf16x8*)(&bLds[cb * 8192 + (wc * 64 + nt * 16 + c16) * 64 + ((0 + q4) ^ x7) * 8]);
#pragma unroll
      for (int mt = 0; mt < 4; mt++)
#pragma unroll
        for (int nt = 0; nt < 4; nt++)
          acc[mt][nt] = __builtin_amdgcn_mfma_f32_16x16x32_bf16(af[mt], bf[nt], acc[mt][nt], 0, 0, 0);
    }
    if (c < 5) { writeA2(nb, 0); loadA2(c + 1, 1); }
    // ks = 1
    {
      bf16x8 af[4], bf[4];
#pragma unroll
      for (int mt = 0; mt < 4; mt++)
        af[mt] = *(const bf16x8*)(&aLds[cb * 8192 + (wr * 64 + mt * 16 + c16) * 64 + ((4 + q4) ^ x7) * 8]);
#pragma unroll
      for (int nt = 0; nt < 4; nt++)
        bf[nt] = *(const bf16x8*)(&bLds[cb * 8192 + (wc * 64 + nt * 16 + c16) * 64 + ((4 + q4) ^ x7) * 8]);
#pragma unroll
      for (int mt = 0; mt < 4; mt++)
#pragma unroll
        for (int nt = 0; nt < 4; nt++)
          acc[mt][nt] = __builtin_amdgcn_mfma_f32_16x16x32_bf16(af[mt], bf[nt], acc[mt][nt], 0, 0, 0);
    }
    if (c < 5) writeA2(nb, 1);
    __syncthreads();
  }

#pragma unroll
  for (int mt = 0; mt < 4; mt++)
#pragma unroll
    for (int nt = 0; nt < 4; nt++) {
      int col = c0 + wc * 64 + nt * 16 + c16;
#pragma unroll
      for (int r = 0; r < 4; r++) {
        int R = (int)rbase + wr * 64 + mt * 16 + q4 * 4 + r;
        int b = R / NTOK;
        if (b >= 4) continue;
        int n = R - b * NTOK;
        int h = col / 48, d = col - h * 48;
        o1[((size_t)(b * 8 + h) * NPAD_Q + n) * 64 + d] =
            f2bf(acc[mt][nt][r] * 0.14433756729740643f);
      }
    }
}

// ---------------- attention body (R2-proven, verbatim; LDS carved from smem) ----------------
__device__ __forceinline__ void attn_body(int vb, u16* smem,
                                          const u16* __restrict__ qb, const u16* __restrict__ kb,
                                          const u16* __restrict__ vt, u16* __restrict__ outb) {
  u16 (*klds)[64][64] = (u16(*)[64][64])(smem);          //  8192 u16
  u16 (*vlds)[48][64] = (u16(*)[48][64])(smem + 8192);   //  6144 u16
  u16 (*plds)[16][76] = (u16(*)[16][76])(smem + 14336);  //  4864 u16
  int tid = threadIdx.x, w = tid >> 6, lane = tid & 63, q4 = lane >> 4, c16 = lane & 15;
  int bh = vb & 31;
  int n0 = (vb >> 5) * 128 + w * 32;
  int r7 = c16 & 7;

  __syncthreads();  // previous grid-stride tile's tail reads of klds[0]/vlds[0] must finish

  const uint4* qp = (const uint4*)(qb + ((size_t)bh * NPAD_Q + n0 + c16) * 64);
  bf16x8 aq[2][2];
#pragma unroll
  for (int rg = 0; rg < 2; rg++) {
    aq[rg][0] = __builtin_bit_cast(bf16x8, qp[rg * 128 + q4]);
    aq[rg][1] = __builtin_bit_cast(bf16x8, qp[rg * 128 + 4 + q4]);
  }

  const u16* kbase = kb + (size_t)bh * KPAD * 64;
  const u16* vbase = vt + (size_t)bh * 48 * KPAD;

  auto stage = [&](int cn, int buf) {
#pragma unroll
    for (int i = 0; i < 2; i++) {
      int s = (w * 2 + i) * 64 + lane;
      int row = s >> 3, chp = s & 7;
      int ch = chp ^ (row & 7);
      gld16(kbase + (size_t)(cn * 64 + row) * 64 + ch * 8, &klds[buf][(w * 2 + i) * 8][0]);
    }
#pragma unroll
    for (int i = 0; i < 2; i++) {
      int blk = w * 2 + i;
      if (blk < 6) {
        int s = blk * 64 + lane;
        int row = s >> 3, chp = s & 7;
        int ch = chp ^ (row & 7);
        gld16(vbase + (size_t)row * KPAD + cn * 64 + ch * 8, &vlds[buf][blk * 8][0]);
      }
    }
  };

  stage(0, 0);
  __syncthreads();

  f32x4 o[2][3];
  float lsum[2][4];
#pragma unroll
  for (int rg = 0; rg < 2; rg++) {
#pragma unroll
    for (int nt = 0; nt < 3; nt++) o[rg][nt] = (f32x4){0, 0, 0, 0};
#pragma unroll
    for (int r = 0; r < 4; r++) lsum[rg][r] = 0.f;
  }

  for (int c = 0; c < 8; c++) {
    int cb = c & 1, nb = cb ^ 1;
    stage(c + 1, nb);  // c=7 stages the tail chunk (keys 512..575) into buffer 0

    f32x4 s[2][4];
#pragma unroll
    for (int rg = 0; rg < 2; rg++)
#pragma unroll
      for (int t = 0; t < 4; t++) s[rg][t] = (f32x4){0, 0, 0, 0};
#pragma unroll
    for (int t = 0; t < 4; t++) {
      const u16* krow = &klds[cb][t * 16 + c16][0];
      bf16x8 k0 = *(const bf16x8*)(krow + (q4 ^ r7) * 8);
      bf16x8 k1 = *(const bf16x8*)(krow + ((q4 ^ r7) ^ 4) * 8);
#pragma unroll
      for (int rg = 0; rg < 2; rg++) {
        s[rg][t] = __builtin_amdgcn_mfma_f32_16x16x32_bf16(aq[rg][0], k0, s[rg][t], 0, 0, 0);
        s[rg][t] = __builtin_amdgcn_mfma_f32_16x16x32_bf16(aq[rg][1], k1, s[rg][t], 0, 0, 0);
      }
    }
#pragma unroll
    for (int rg = 0; rg < 2; rg++)
#pragma unroll
      for (int t = 0; t < 4; t++)
#pragma unroll
        for (int r = 0; r < 4; r++) {
          float e = __expf(s[rg][t][r]);
          s[rg][t][r] = e;
          lsum[rg][r] += e;
        }
    bf16x8 afrag[2][2];
#pragma unroll
    for (int rg = 0; rg < 2; rg++) {
#pragma unroll
      for (int t = 0; t < 4; t++)
#pragma unroll
        for (int r = 0; r < 4; r++) plds[w][q4 * 4 + r][t * 16 + c16] = f2bf_fast(s[rg][t][r]);
#pragma unroll
      for (int kl = 0; kl < 2; kl++)
        afrag[rg][kl] = *(const bf16x8*)(&plds[w][c16][kl * 32 + q4 * 8]);
    }
#pragma unroll
    for (int kl = 0; kl < 2; kl++)
#pragma unroll
      for (int nt = 0; nt < 3; nt++) {
        const u16* vrow = &vlds[cb][nt * 16 + c16][0];
        bf16x8 bv = *(const bf16x8*)(vrow + ((kl * 4 + q4) ^ r7) * 8);
#pragma unroll
        for (int rg = 0; rg < 2; rg++)
          o[rg][nt] = __builtin_amdgcn_mfma_f32_16x16x32_bf16(afrag[rg][kl], bv, o[rg][nt], 0, 0, 0);
      }
    __syncthreads();
  }

  // tail: keys 512..527 staged in buffer 0; only key 512 (c16==0) valid
  {
    f32x4 s4[2] = {{0, 0, 0, 0}, {0, 0, 0, 0}};
    const u16* krow = &klds[0][c16][0];
    bf16x8 k0 = *(const bf16x8*)(krow + (q4 ^ r7) * 8);
    bf16x8 k1 = *(const bf16x8*)(krow + ((q4 ^ r7) ^ 4) * 8);
#pragma unroll
    for (int rg = 0; rg < 2; rg++) {
      s4[rg] = __builtin_amdgcn_mfma_f32_16x16x32_bf16(aq[rg][0], k0, s4[rg], 0, 0, 0);
      s4[rg] = __builtin_amdgcn_mfma_f32_16x16x32_bf16(aq[rg][1], k1, s4[rg], 0, 0, 0);
    }
    bf16x8 afrag[2];
#pragma unroll
    for (int rg = 0; rg < 2; rg++) {
#pragma unroll
      for (int r = 0; r < 4; r++) {
        float e = (c16 == 0) ? __expf(s4[rg][r]) : 0.f;
        lsum[rg][r] += e;
        plds[w][q4 * 4 + r][c16] = f2bf_fast(e);
        plds[w][q4 * 4 + r][16 + c16] = 0;
      }
      afrag[rg] = *(const bf16x8*)(&plds[w][c16][q4 * 8]);
    }
#pragma unroll
    for (int nt = 0; nt < 3; nt++) {
      const u16* vrow = &vlds[0][nt * 16 + c16][0];
      bf16x8 bv = *(const bf16x8*)(vrow + (q4 ^ r7) * 8);
#pragma unroll
      for (int rg = 0; rg < 2; rg++)
        o[rg][nt] = __builtin_amdgcn_mfma_f32_16x16x32_bf16(afrag[rg], bv, o[rg][nt], 0, 0, 0);
    }
  }

  int b = bh >> 3, h = bh & 7;
#pragma unroll
  for (int rg = 0; rg < 2; rg++) {
    float inv[4];
#pragma unroll
    for (int r = 0; r < 4; r++) {
      float l = lsum[rg][r];
      l += __shfl_xor(l, 1);
      l += __shfl_xor(l, 2);
      l += __shfl_xor(l, 4);
      l += __shfl_xor(l, 8);
      inv[r] = 1.0f / l;
    }
#pragma unroll
    for (int nt = 0; nt < 3; nt++)
#pragma unroll
      for (int r = 0; r < 4; r++) {
        int n = n0 + rg * 16 + q4 * 4 + r;
        if (n < NTOK) outb[((size_t)(b * NTOK + n)) * 384 + h * 48 + nt * 16 + c16] = f2bf(o[rg][nt][r] * inv[r]);
      }
  }
}

// ---------------- mega kernel: 4 phases in one dispatch, manual grid barriers ----------------
__global__ __launch_bounds__(256, 2) void mega_kernel(
    const float* __restrict__ x, const float* __restrict__ qw, const float* __restrict__ kvw,
    const float* __restrict__ pw, const float* __restrict__ pb,
    const float* __restrict__ srw, const float* __restrict__ srb,
    const float* __restrict__ lng, const float* __restrict__ lnb,
    u16* __restrict__ qwb, u16* __restrict__ kvwb, u16* __restrict__ pwb,
    u16* __restrict__ xln, u16* __restrict__ qb, u16* __restrict__ kb, u16* __restrict__ vtb,
    u16* attnb, float* __restrict__ out, u32* bar) {
  __shared__ __align__(16) u16 smem[32768];  // 64 KB -> 2 blocks/CU
  int tid = threadIdx.x;

  // barrier-area init (workspace is re-poisoned each iteration; 0xAAAAAAAA != MAGIC)
  if (blockIdx.x == 0 && tid == 0) {
    bar[1] = 0; bar[2] = 0; bar[3] = 0;
    __threadfence();
    __hip_atomic_store(&bar[0], MAGIC, __ATOMIC_RELEASE, __HIP_MEMORY_SCOPE_AGENT);
  }
  if (tid == 0) {
    while (__hip_atomic_load(&bar[0], __ATOMIC_ACQUIRE, __HIP_MEMORY_SCOPE_AGENT) != MAGIC)
      __builtin_amdgcn_s_sleep(2);
  }
  __syncthreads();

  // ---- P0: sr_ln (256-thread re-lane) + weight casts ----
  for (int vb = blockIdx.x; vb < P0_N; vb += NBLK) {
    if (vb < P0_SRLN) {
      int b = vb / MTOK, m = vb - b * MTOK;
      float v0 = srln_val(x, srw, srb, b, m, tid);
      bool has2 = tid < 128;
      float v1 = has2 ? srln_val(x, srw, srb, b, m, tid + 256) : 0.f;
      float s1 = v0 + v1, s2 = v0 * v0 + v1 * v1;
#pragma unroll
      for (int msk = 32; msk >= 1; msk >>= 1) {
        s1 += __shfl_xor(s1, msk);
        s2 += __shfl_xor(s2, msk);
      }
      float* r1 = (float*)smem;
      float* r2 = r1 + 4;
      int w = tid >> 6, lane = tid & 63;
      if (lane == 0) { r1[w] = s1; r2[w] = s2; }
      __syncthreads();
      float S1 = r1[0] + r1[1] + r1[2] + r1[3];
      float S2 = r2[0] + r2[1] + r2[2] + r2[3];
      float mu = S1 * (1.0f / 384.0f);
      float var = S2 * (1.0f / 384.0f) - mu * mu;
      float rs = rsqrtf(var + 1e-5f);
      size_t rowb = (size_t)(b * MPAD + m) * 384;
      xln[rowb + tid] = f2bf((v0 - mu) * rs * lng[tid] + lnb[tid]);
      if (has2) xln[rowb + tid + 256] = f2bf((v1 - mu) * rs * lng[tid + 256] + lnb[tid + 256]);
      __syncthreads();  // r1/r2 reused next grid-stride iteration
    } else {
      int g = (vb - P0_SRLN) * 256 + tid;  // < GW exactly
      const float* s;
      u16* d;
      int off;
      if (g < GQW) { s = qw; d = qwb; off = g * 8; }
      else if (g < GQW + GKVW) { s = kvw; d = kvwb; off = (g - GQW) * 8; }
      else { s = pw; d = pwb; off = (g - GQW - GKVW) * 8; }
      float4 v0 = *(const float4*)(s + off);
      float4 v1 = *(const float4*)(s + off + 4);
      uint4 o;
      u16* p = (u16*)&o;
      p[0] = f2bf(v0.x); p[1] = f2bf(v0.y); p[2] = f2bf(v0.z); p[3] = f2bf(v0.w);
      p[4] = f2bf(v1.x); p[5] = f2bf(v1.y); p[6] = f2bf(v1.z); p[7] = f2bf(v1.w);
      *(uint4*)(d + off) = o;
    }
  }
  gbar(bar + 1);

  // ---- P1: q-proj (f32 A) + kv-proj ----
  for (int vb = blockIdx.x; vb < P1_N; vb += NBLK) {
    if (vb < 387) {
      gemm_core_f32A(smem, smem + 16384, x, qwb, (size_t)(vb % 129) * 128, (vb / 129) * 128, qb);
    } else {
      int i = vb - 387;
      gemm_core(smem, smem + 16384, xln, kvwb, 1, (size_t)(i % 17) * 128, (i / 17) * 128,
                kb, vtb, nullptr, nullptr);
    }
  }
  gbar(bar + 2);

  // ---- P2: attention ----
  for (int vb = blockIdx.x; vb < P2_N; vb += NBLK)
    attn_body(vb, smem, qb, kb, vtb, attnb);
  gbar(bar + 3);

  // ---- P3: out-proj ----
  for (int vb = blockIdx.x; vb < P3_N; vb += NBLK)
    gemm_core(smem, smem + 16384, attnb, pwb, 2, (size_t)(vb % 129) * 128, (vb / 129) * 128,
              nullptr, nullptr, out, pb);
}

extern "C" void kernel_launch(void* const* d_in, const int* in_sizes, int n_in,
                              void* d_out, int out_size, void* d_ws, size_t ws_size,
                              hipStream_t stream) {
  const float* x = (const float*)d_in[0];
  const float* q_w = (const float*)d_in[1];
  const float* kv_w = (const float*)d_in[2];
  const float* proj_w = (const float*)d_in[3];
  const float* proj_b = (const float*)d_in[4];
  const float* sr_w = (const float*)d_in[5];
  const float* sr_b = (const float*)d_in[6];
  const float* ln_g = (const float*)d_in[7];
  const float* ln_b = (const float*)d_in[8];
  float* out = (float*)d_out;

  u16* ws = (u16*)d_ws;
  u16* x_b = ws;                          // region used only as attn output now
  u16* qw_b = x_b + (size_t)ROWS_X * 384; // 147,456
  u16* kvw_b = qw_b + 147456;             // 294,912
  u16* pw_b = kvw_b + 294912;             // 147,456
  u16* q_b = pw_b + 147456;               // 32*4224*64      = 8,650,752
  u16* xln_b = q_b + (size_t)32 * NPAD_Q * 64;  // 4*544*384 = 835,584
  u16* k_b = xln_b + (size_t)4 * MPAD * 384;    // 32*640*64 = 1,310,720
  u16* vt_b = k_b + (size_t)32 * KPAD * 64;     // 32*48*640 = 983,040
  u16* attn_b = x_b;
  u32* bar = (u32*)(ws + (size_t)60 * 1024 * 1024);  // 120 MB into ws, far from live data

  mega_kernel<<<NBLK, 256, 0, stream>>>(x, q_w, kv_w, proj_w, proj_b, sr_w, sr_b, ln_g, ln_b,
                                        qw_b, kvw_b, pw_b, xln_b, q_b, k_b, vt_b, attn_b, out, bar);
}

// Round 6
// 308.049 us; speedup vs baseline: 1.4792x; 1.4792x over previous
//
#include <hip/hip_runtime.h>

typedef unsigned short u16;
typedef unsigned int u32;
typedef __bf16 bf16x8 __attribute__((ext_vector_type(8)));
typedef float f32x4 __attribute__((ext_vector_type(4)));

#define NTOK 4097
#define MTOK 513
#define MPAD 544     // 34*16 (xln row padding)
#define KPAD 640     // K/V padded
#define NPAD_Q 4224  // 33*128
#define ROWS_X 16512 // 129*128

__device__ __forceinline__ u16 f2bf(float f) {  // RNE (outputs)
  u32 u = __builtin_bit_cast(u32, f);
  u = u + 0x7FFFu + ((u >> 16) & 1u);
  return (u16)(u >> 16);
}
__device__ __forceinline__ u16 f2bf_fast(float f) {  // round-half-up (internal P)
  u32 u = __builtin_bit_cast(u32, f);
  return (u16)((u + 0x8000u) >> 16);
}

// async global->LDS DMA, 16B per lane; LDS dest = wave-uniform base + lane*16
__device__ __forceinline__ void gld16(const u16* g, u16* l) {
  __builtin_amdgcn_global_load_lds((const __attribute__((address_space(1))) u32*)g,
                                   (__attribute__((address_space(3))) u32*)l, 16, 0, 0);
}

#define GPW  18432   // 147456/8 pw 8-elem groups
#define KV_BLOCKS 34 // 17 row-tiles x 2 col-groups
#define Q_BLOCKS  387
#define PW_BLOCKS 72 // 72*256 = 18432 exactly

// ---------------- per-channel sr-conv value (verbatim math) ----------------
__device__ __forceinline__ float srln_val(const float* __restrict__ x, const float* __restrict__ srw,
                                          const float* __restrict__ srb, int b, int m, int c) {
  if (m == 0) return x[(b * NTOK) * 384 + c];
  int mo = m - 1;
  int oz = mo >> 6, oy = (mo >> 3) & 7, ox = mo & 7;
  float acc = srb[c];
#pragma unroll
  for (int dz = 0; dz < 2; dz++)
#pragma unroll
    for (int dy = 0; dy < 2; dy++)
#pragma unroll
      for (int dx = 0; dx < 2; dx++) {
        int tok = 1 + ((2 * oz + dz) * 256 + (2 * oy + dy) * 16 + (2 * ox + dx));
        acc += x[(b * NTOK + tok) * 384 + c] * srw[c * 8 + dz * 4 + dy * 2 + dx];
      }
  return acc;
}

// ---------------- sr_ln for one 128-row tile, computed by one block ----------------
// wave w owns rows w*32..w*32+31; lane owns 6 channels; full-wave shfl reduce.
// Writes xln rows rbase..rbase+127 (pad rows m>=513 left as poison, same as before).
__device__ __forceinline__ void srln_tile128(const float* __restrict__ x,
                                             const float* __restrict__ srw, const float* __restrict__ srb,
                                             const float* __restrict__ lng, const float* __restrict__ lnb,
                                             int rbase, u16* __restrict__ xln) {
  int tid = threadIdx.x, w = tid >> 6, lane = tid & 63;
  int ch0 = lane * 6;
  for (int jj = 0; jj < 32; jj++) {
    int R = rbase + w * 32 + jj;
    int b = R / MPAD, m = R - b * MPAD;
    if (m >= MTOK) continue;  // wave-uniform (R uniform per wave)
    float vv[6];
    float s1 = 0.f, s2 = 0.f;
#pragma unroll
    for (int k = 0; k < 6; k++) {
      float v = srln_val(x, srw, srb, b, m, ch0 + k);
      vv[k] = v;
      s1 += v;
      s2 += v * v;
    }
#pragma unroll
    for (int msk = 32; msk >= 1; msk >>= 1) {
      s1 += __shfl_xor(s1, msk);
      s2 += __shfl_xor(s2, msk);
    }
    float mu = s1 * (1.0f / 384.0f);
    float var = s2 * (1.0f / 384.0f) - mu * mu;
    float rs = rsqrtf(var + 1e-5f);
    u16* dst = xln + (size_t)(b * MPAD + m) * 384 + ch0;
#pragma unroll
    for (int k = 0; k < 6; k++)
      dst[k] = f2bf((vv[k] - mu) * rs * lng[ch0 + k] + lnb[ch0 + k]);
  }
}

// ---------------- GEMM core (R2-proven dbuf body, verbatim; used by out-proj, mode 2) ----------------
__device__ __forceinline__ void gemm_core(u16* aLds, u16* bLds,
                                          const u16* __restrict__ A, const u16* __restrict__ W,
                                          int mode, size_t rbase, int c0,
                                          u16* __restrict__ o1, u16* __restrict__ o2,
                                          float* __restrict__ of, const float* __restrict__ bias) {
  int tid = threadIdx.x, w = tid >> 6, lane = tid & 63, q4 = lane >> 4, c16 = lane & 15;
  int wr = w >> 1, wc = w & 1;
  int x7 = c16 & 7;

  auto stageAB = [&](int kc, int buf) {
#pragma unroll
    for (int i = 0; i < 4; i++) {
      int s = (w * 4 + i) * 64 + lane;
      int row = s >> 3, chp = s & 7;
      int ch = chp ^ (row & 7);
      gld16(A + (rbase + row) * 384 + kc * 64 + ch * 8, &aLds[buf * 8192 + (w * 4 + i) * 512]);
    }
#pragma unroll
    for (int i = 0; i < 4; i++) {
      int s = (w * 4 + i) * 64 + lane;
      int row = s >> 3, chp = s & 7;
      int ch = chp ^ (row & 7);
      gld16(W + (size_t)(c0 + row) * 384 + kc * 64 + ch * 8, &bLds[buf * 8192 + (w * 4 + i) * 512]);
    }
  };
  stageAB(0, 0);
  __syncthreads();

  f32x4 acc[4][4];
#pragma unroll
  for (int mt = 0; mt < 4; mt++)
#pragma unroll
    for (int nt = 0; nt < 4; nt++) acc[mt][nt] = (f32x4){0, 0, 0, 0};

  for (int c = 0; c < 6; c++) {
    int cb = c & 1, nb = cb ^ 1;
    if (c < 5) stageAB(c + 1, nb);  // async; drains at this iter's end barrier
#pragma unroll
    for (int ks = 0; ks < 2; ks++) {
      bf16x8 af[4], bf[4];
#pragma unroll
      for (int mt = 0; mt < 4; mt++)
        af[mt] = *(const bf16x8*)(&aLds[cb * 8192 + (wr * 64 + mt * 16 + c16) * 64 + ((ks * 4 + q4) ^ x7) * 8]);
#pragma unroll
      for (int nt = 0; nt < 4; nt++)
        bf[nt] = *(const bf16x8*)(&bLds[cb * 8192 + (wc * 64 + nt * 16 + c16) * 64 + ((ks * 4 + q4) ^ x7) * 8]);
#pragma unroll
      for (int mt = 0; mt < 4; mt++)
#pragma unroll
        for (int nt = 0; nt < 4; nt++)
          acc[mt][nt] = __builtin_amdgcn_mfma_f32_16x16x32_bf16(af[mt], bf[nt], acc[mt][nt], 0, 0, 0);
    }
    __syncthreads();
  }

#pragma unroll
  for (int mt = 0; mt < 4; mt++)
#pragma unroll
    for (int nt = 0; nt < 4; nt++) {
      int col = c0 + wc * 64 + nt * 16 + c16;
#pragma unroll
      for (int r = 0; r < 4; r++) {
        int R = (int)rbase + wr * 64 + mt * 16 + q4 * 4 + r;
        float val = acc[mt][nt][r];
        if (mode == 1) {
          int b = R / MPAD;
          int m = R - b * MPAD;
          if (col < 384) {
            int h = col / 48, d = col - h * 48;
            o1[((size_t)(b * 8 + h) * KPAD + m) * 64 + d] = f2bf(val);
          } else {
            int c2 = col - 384;
            int h = c2 / 48, d = c2 - h * 48;
            o2[((size_t)(b * 8 + h) * 48 + d) * KPAD + m] = f2bf(val);
          }
        } else {
          if (R < 4 * NTOK) of[(size_t)R * 384 + col] = val + bias[col];
        }
      }
    }
}

// ---------------- q-proj core: A = x (f32), B = qw (f32), both reg-cast staged ----------------
// Extends the R2-proven f32A half-split to the B operand. Same LDS slots/swizzle as gld16
// would produce from pre-cast bf16 -> bit-identical math to the R2 pipeline.
__device__ __forceinline__ void gemm_q_f32ab(u16* aLds, u16* bLds,
                                             const float* __restrict__ X, const float* __restrict__ QW,
                                             size_t rbase, int c0, u16* __restrict__ o1) {
  int tid = threadIdx.x, w = tid >> 6, lane = tid & 63, q4 = lane >> 4, c16 = lane & 15;
  int wr = w >> 1, wc = w & 1;
  int x7 = c16 & 7;

  float4 ra[2][2], rb[2][2];
  auto loadA2 = [&](int kc, int half) {
#pragma unroll
    for (int i = 0; i < 2; i++) {
      int idx2 = half * 2 + i;
      int s = (w * 4 + idx2) * 64 + lane;
      int row = s >> 3, chp = s & 7;
      int ch = chp ^ (row & 7);
      int ar = (int)rbase + row;
      if (ar > 16387) ar = 16387;  // clamp pad rows (outputs discarded: b>=4)
      const float* pa = X + (size_t)ar * 384 + kc * 64 + ch * 8;
      ra[i][0] = *(const float4*)pa;
      ra[i][1] = *(const float4*)(pa + 4);
    }
  };
  auto loadB2 = [&](int kc, int half) {
#pragma unroll
    for (int i = 0; i < 2; i++) {
      int idx2 = half * 2 + i;
      int s = (w * 4 + idx2) * 64 + lane;
      int row = s >> 3, chp = s & 7;
      int ch = chp ^ (row & 7);
      const float* pb = QW + (size_t)(c0 + row) * 384 + kc * 64 + ch * 8;
      rb[i][0] = *(const float4*)pb;
      rb[i][1] = *(const float4*)(pb + 4);
    }
  };
  auto writeA2 = [&](int buf, int half) {
#pragma unroll
    for (int i = 0; i < 2; i++) {
      int idx2 = half * 2 + i;
      uint4 oa;
      u16* p = (u16*)&oa;
      p[0] = f2bf(ra[i][0].x); p[1] = f2bf(ra[i][0].y);
      p[2] = f2bf(ra[i][0].z); p[3] = f2bf(ra[i][0].w);
      p[4] = f2bf(ra[i][1].x); p[5] = f2bf(ra[i][1].y);
      p[6] = f2bf(ra[i][1].z); p[7] = f2bf(ra[i][1].w);
      *(uint4*)(&aLds[buf * 8192 + (w * 4 + idx2) * 512 + lane * 8]) = oa;
    }
  };
  auto writeB2 = [&](int buf, int half) {
#pragma unroll
    for (int i = 0; i < 2; i++) {
      int idx2 = half * 2 + i;
      uint4 ob;
      u16* p = (u16*)&ob;
      p[0] = f2bf(rb[i][0].x); p[1] = f2bf(rb[i][0].y);
      p[2] = f2bf(rb[i][0].z); p[3] = f2bf(rb[i][0].w);
      p[4] = f2bf(rb[i][1].x); p[5] = f2bf(rb[i][1].y);
      p[6] = f2bf(rb[i][1].z); p[7] = f2bf(rb[i][1].w);
      *(uint4*)(&bLds[buf * 8192 + (w * 4 + idx2) * 512 + lane * 8]) = ob;
    }
  };

  loadA2(0, 0); loadB2(0, 0);
  writeA2(0, 0); writeB2(0, 0);
  loadA2(0, 1); loadB2(0, 1);
  writeA2(0, 1); writeB2(0, 1);
  __syncthreads();

  f32x4 acc[4][4];
#pragma unroll
  for (int mt = 0; mt < 4; mt++)
#pragma unroll
    for (int nt = 0; nt < 4; nt++) acc[mt][nt] = (f32x4){0, 0, 0, 0};

  for (int c = 0; c < 6; c++) {
    int cb = c & 1, nb = cb ^ 1;
    if (c < 5) { loadA2(c + 1, 0); loadB2(c + 1, 0); }
    // ks = 0
    {
      bf16x8 af[4], bf[4];
#pragma unroll
      for (int mt = 0; mt < 4; mt++)
        af[mt] = *(const bf16x8*)(&aLds[cb * 8192 + (wr * 64 + mt * 16 + c16) * 64 + ((0 + q4) ^ x7) * 8]);
#pragma unroll
      for (int nt = 0; nt < 4; nt++)
        bf[nt] = *(const bf16x8*)(&bLds[cb * 8192 + (wc * 64 + nt * 16 + c16) * 64 + ((0 + q4) ^ x7) * 8]);
#pragma unroll
      for (int mt = 0; mt < 4; mt++)
#pragma unroll
        for (int nt = 0; nt < 4; nt++)
          acc[mt][nt] = __builtin_amdgcn_mfma_f32_16x16x32_bf16(af[mt], bf[nt], acc[mt][nt], 0, 0, 0);
    }
    if (c < 5) { writeA2(nb, 0); writeB2(nb, 0); loadA2(c + 1, 1); loadB2(c + 1, 1); }
    // ks = 1
    {
      bf16x8 af[4], bf[4];
#pragma unroll
      for (int mt = 0; mt < 4; mt++)
        af[mt] = *(const bf16x8*)(&aLds[cb * 8192 + (wr * 64 + mt * 16 + c16) * 64 + ((4 + q4) ^ x7) * 8]);
#pragma unroll
      for (int nt = 0; nt < 4; nt++)
        bf[nt] = *(const bf16x8*)(&bLds[cb * 8192 + (wc * 64 + nt * 16 + c16) * 64 + ((4 + q4) ^ x7) * 8]);
#pragma unroll
      for (int mt = 0; mt < 4; mt++)
#pragma unroll
        for (int nt = 0; nt < 4; nt++)
          acc[mt][nt] = __builtin_amdgcn_mfma_f32_16x16x32_bf16(af[mt], bf[nt], acc[mt][nt], 0, 0, 0);
    }
    if (c < 5) { writeA2(nb, 1); writeB2(nb, 1); }
    __syncthreads();
  }

#pragma unroll
  for (int mt = 0; mt < 4; mt++)
#pragma unroll
    for (int nt = 0; nt < 4; nt++) {
      int col = c0 + wc * 64 + nt * 16 + c16;
#pragma unroll
      for (int r = 0; r < 4; r++) {
        int R = (int)rbase + wr * 64 + mt * 16 + q4 * 4 + r;
        int b = R / NTOK;
        if (b >= 4) continue;
        int n = R - b * NTOK;
        int h = col / 48, d = col - h * 48;
        o1[((size_t)(b * 8 + h) * NPAD_Q + n) * 64 + d] =
            f2bf(acc[mt][nt][r] * 0.14433756729740643f);
      }
    }
}

// ---------------- kv-proj core: A = xln (bf16, self-written) via gld16, B = kvw (f32) reg-cast ----
__device__ __forceinline__ void gemm_kv_f32b(u16* aLds, u16* bLds,
                                             const u16* A, const float* __restrict__ KVW,
                                             size_t rbase, int c0,
                                             u16* __restrict__ o1, u16* __restrict__ o2) {
  int tid = threadIdx.x, w = tid >> 6, lane = tid & 63, q4 = lane >> 4, c16 = lane & 15;
  int wr = w >> 1, wc = w & 1;
  int x7 = c16 & 7;

  auto stageA = [&](int kc, int buf) {
#pragma unroll
    for (int i = 0; i < 4; i++) {
      int s = (w * 4 + i) * 64 + lane;
      int row = s >> 3, chp = s & 7;
      int ch = chp ^ (row & 7);
      gld16(A + (rbase + row) * 384 + kc * 64 + ch * 8, &aLds[buf * 8192 + (w * 4 + i) * 512]);
    }
  };
  float4 rb[2][2];
  auto loadB2 = [&](int kc, int half) {
#pragma unroll
    for (int i = 0; i < 2; i++) {
      int idx2 = half * 2 + i;
      int s = (w * 4 + idx2) * 64 + lane;
      int row = s >> 3, chp = s & 7;
      int ch = chp ^ (row & 7);
      const float* pb = KVW + (size_t)(c0 + row) * 384 + kc * 64 + ch * 8;
      rb[i][0] = *(const float4*)pb;
      rb[i][1] = *(const float4*)(pb + 4);
    }
  };
  auto writeB2 = [&](int buf, int half) {
#pragma unroll
    for (int i = 0; i < 2; i++) {
      int idx2 = half * 2 + i;
      uint4 ob;
      u16* p = (u16*)&ob;
      p[0] = f2bf(rb[i][0].x); p[1] = f2bf(rb[i][0].y);
      p[2] = f2bf(rb[i][0].z); p[3] = f2bf(rb[i][0].w);
      p[4] = f2bf(rb[i][1].x); p[5] = f2bf(rb[i][1].y);
      p[6] = f2bf(rb[i][1].z); p[7] = f2bf(rb[i][1].w);
      *(uint4*)(&bLds[buf * 8192 + (w * 4 + idx2) * 512 + lane * 8]) = ob;
    }
  };

  stageA(0, 0);
  loadB2(0, 0); writeB2(0, 0);
  loadB2(0, 1); writeB2(0, 1);
  __syncthreads();

  f32x4 acc[4][4];
#pragma unroll
  for (int mt = 0; mt < 4; mt++)
#pragma unroll
    for (int nt = 0; nt < 4; nt++) acc[mt][nt] = (f32x4){0, 0, 0, 0};

  for (int c = 0; c < 6; c++) {
    int cb = c & 1, nb = cb ^ 1;
    if (c < 5) { stageA(c + 1, nb); loadB2(c + 1, 0); }
    // ks = 0
    {
      bf16x8 af[4], bf[4];
#pragma unroll
      for (int mt = 0; mt < 4; mt++)
        af[mt] = *(const bf16x8*)(&aLds[cb * 8192 + (wr * 64 + mt * 16 + c16) * 64 + ((0 + q4) ^ x7) * 8]);
#pragma unroll
      for (int nt = 0; nt < 4; nt++)
        bf[nt] = *(const bf16x8*)(&bLds[cb * 8192 + (wc * 64 + nt * 16 + c16) * 64 + ((0 + q4) ^ x7) * 8]);
#pragma unroll
      for (int mt = 0; mt < 4; mt++)
#pragma unroll
        for (int nt = 0; nt < 4; nt++)
          acc[mt][nt] = __builtin_amdgcn_mfma_f32_16x16x32_bf16(af[mt], bf[nt], acc[mt][nt], 0, 0, 0);
    }
    if (c < 5) { writeB2(nb, 0); loadB2(c + 1, 1); }
    // ks = 1
    {
      bf16x8 af[4], bf[4];
#pragma unroll
      for (int mt = 0; mt < 4; mt++)
        af[mt] = *(const bf16x8*)(&aLds[cb * 8192 + (wr * 64 + mt * 16 + c16) * 64 + ((4 + q4) ^ x7) * 8]);
#pragma unroll
      for (int nt = 0; nt < 4; nt++)
        bf[nt] = *(const bf16x8*)(&bLds[cb * 8192 + (wc * 64 + nt * 16 + c16) * 64 + ((4 + q4) ^ x7) * 8]);
#pragma unroll
      for (int mt = 0; mt < 4; mt++)
#pragma unroll
        for (int nt = 0; nt < 4; nt++)
          acc[mt][nt] = __builtin_amdgcn_mfma_f32_16x16x32_bf16(af[mt], bf[nt], acc[mt][nt], 0, 0, 0);
    }
    if (c < 5) writeB2(nb, 1);
    __syncthreads();
  }

#pragma unroll
  for (int mt = 0; mt < 4; mt++)
#pragma unroll
    for (int nt = 0; nt < 4; nt++) {
      int col = c0 + wc * 64 + nt * 16 + c16;
#pragma unroll
      for (int r = 0; r < 4; r++) {
        int R = (int)rbase + wr * 64 + mt * 16 + q4 * 4 + r;
        float val = acc[mt][nt][r];
        int b = R / MPAD;
        int m = R - b * MPAD;
        if (col < 384) {
          int h = col / 48, d = col - h * 48;
          o1[((size_t)(b * 8 + h) * KPAD + m) * 64 + d] = f2bf(val);
        } else {
          int c2 = col - 384;
          int h = c2 / 48, d = c2 - h * 48;
          o2[((size_t)(b * 8 + h) * 48 + d) * KPAD + m] = f2bf(val);
        }
      }
    }
}

// ---------------- K1: fused {kv: srln+kv-proj} + {q-proj f32 A/B} + {pw cast} ----------------
__global__ __launch_bounds__(256) void fused_qkv(
    const float* __restrict__ x, const float* __restrict__ qw, const float* __restrict__ kvw,
    const float* __restrict__ pw, const float* __restrict__ srw, const float* __restrict__ srb,
    const float* __restrict__ lng, const float* __restrict__ lnb,
    u16* __restrict__ qb, u16* __restrict__ kb, u16* __restrict__ vtb,
    u16* xln, u16* __restrict__ pwb) {
  __shared__ __align__(16) u16 aLds[2 * 128 * 64];
  __shared__ __align__(16) u16 bLds[2 * 128 * 64];
  int bx = blockIdx.x;
  if (bx < KV_BLOCKS) {
    int rt = bx >> 1, cg = bx & 1;  // row-tile 0..16, col-group 0..1
    srln_tile128(x, srw, srb, lng, lnb, rt * 128, xln);
    __syncthreads();  // all waves' xln stores drained (vmcnt0 before barrier)
    for (int t = 0; t < 3; t++)
      gemm_kv_f32b(aLds, bLds, xln, kvw, (size_t)rt * 128, cg * 384 + t * 128, kb, vtb);
  } else if (bx < KV_BLOCKS + Q_BLOCKS) {
    int i = bx - KV_BLOCKS;
    gemm_q_f32ab(aLds, bLds, x, qw, (size_t)(i % 129) * 128, (i / 129) * 128, qb);
  } else {
    int g = (bx - KV_BLOCKS - Q_BLOCKS) * 256 + threadIdx.x;  // < GPW exactly
    int off = g * 8;
    float4 v0 = *(const float4*)(pw + off);
    float4 v1 = *(const float4*)(pw + off + 4);
    uint4 o;
    u16* p = (u16*)&o;
    p[0] = f2bf(v0.x); p[1] = f2bf(v0.y); p[2] = f2bf(v0.z); p[3] = f2bf(v0.w);
    p[4] = f2bf(v1.x); p[5] = f2bf(v1.y); p[6] = f2bf(v1.z); p[7] = f2bf(v1.w);
    *(uint4*)(pwb + off) = o;
  }
}

// out-proj (mode 2)
__global__ __launch_bounds__(256) void gemm_out(const u16* __restrict__ A, const u16* __restrict__ W,
                                                float* __restrict__ of, const float* __restrict__ bias) {
  __shared__ __align__(16) u16 aLds[2 * 128 * 64];
  __shared__ __align__(16) u16 bLds[2 * 128 * 64];
  gemm_core(aLds, bLds, A, W, 2, (size_t)blockIdx.x * 128, blockIdx.y * 128,
            nullptr, nullptr, of, bias);
}

// ---------------- Attention (R2-proven, verbatim) ----------------
__global__ __launch_bounds__(256, 4) void attn_kernel(const u16* __restrict__ qb,
                                                      const u16* __restrict__ kb,
                                                      const u16* __restrict__ vt,
                                                      u16* __restrict__ outb) {
  __shared__ __align__(16) u16 klds[2][64][64];   // 16,384 B (unpadded: DMA dest)
  __shared__ __align__(16) u16 vlds[2][48][64];   // 12,288 B
  __shared__ __align__(16) u16 plds[4][16][76];   //  9,728 B (wave-private P scratch)
  int tid = threadIdx.x, w = tid >> 6, lane = tid & 63, q4 = lane >> 4, c16 = lane & 15;
  int bh = blockIdx.x;
  int n0 = blockIdx.y * 128 + w * 32;
  int r7 = c16 & 7;

  const uint4* qp = (const uint4*)(qb + ((size_t)bh * NPAD_Q + n0 + c16) * 64);
  bf16x8 aq[2][2];
#pragma unroll
  for (int rg = 0; rg < 2; rg++) {
    aq[rg][0] = __builtin_bit_cast(bf16x8, qp[rg * 128 + q4]);
    aq[rg][1] = __builtin_bit_cast(bf16x8, qp[rg * 128 + 4 + q4]);
  }

  const u16* kbase = kb + (size_t)bh * KPAD * 64;
  const u16* vbase = vt + (size_t)bh * 48 * KPAD;

  auto stage = [&](int cn, int buf) {
#pragma unroll
    for (int i = 0; i < 2; i++) {
      int s = (w * 2 + i) * 64 + lane;
      int row = s >> 3, chp = s & 7;
      int ch = chp ^ (row & 7);
      gld16(kbase + (size_t)(cn * 64 + row) * 64 + ch * 8, &klds[buf][(w * 2 + i) * 8][0]);
    }
#pragma unroll
    for (int i = 0; i < 2; i++) {
      int blk = w * 2 + i;
      if (blk < 6) {
        int s = blk * 64 + lane;
        int row = s >> 3, chp = s & 7;
        int ch = chp ^ (row & 7);
        gld16(vbase + (size_t)row * KPAD + cn * 64 + ch * 8, &vlds[buf][blk * 8][0]);
      }
    }
  };

  stage(0, 0);
  __syncthreads();

  f32x4 o[2][3];
  float lsum[2][4];
#pragma unroll
  for (int rg = 0; rg < 2; rg++) {
#pragma unroll
    for (int nt = 0; nt < 3; nt++) o[rg][nt] = (f32x4){0, 0, 0, 0};
#pragma unroll
    for (int r = 0; r < 4; r++) lsum[rg][r] = 0.f;
  }

  for (int c = 0; c < 8; c++) {
    int cb = c & 1, nb = cb ^ 1;
    stage(c + 1, nb);  // c=7 stages the tail chunk (keys 512..575) into buffer 0

    f32x4 s[2][4];
#pragma unroll
    for (int rg = 0; rg < 2; rg++)
#pragma unroll
      for (int t = 0; t < 4; t++) s[rg][t] = (f32x4){0, 0, 0, 0};
#pragma unroll
    for (int t = 0; t < 4; t++) {
      const u16* krow = &klds[cb][t * 16 + c16][0];
      bf16x8 k0 = *(const bf16x8*)(krow + (q4 ^ r7) * 8);
      bf16x8 k1 = *(const bf16x8*)(krow + ((q4 ^ r7) ^ 4) * 8);
#pragma unroll
      for (int rg = 0; rg < 2; rg++) {
        s[rg][t] = __builtin_amdgcn_mfma_f32_16x16x32_bf16(aq[rg][0], k0, s[rg][t], 0, 0, 0);
        s[rg][t] = __builtin_amdgcn_mfma_f32_16x16x32_bf16(aq[rg][1], k1, s[rg][t], 0, 0, 0);
      }
    }
#pragma unroll
    for (int rg = 0; rg < 2; rg++)
#pragma unroll
      for (int t = 0; t < 4; t++)
#pragma unroll
        for (int r = 0; r < 4; r++) {
          float e = __expf(s[rg][t][r]);
          s[rg][t][r] = e;
          lsum[rg][r] += e;
        }
    bf16x8 afrag[2][2];
#pragma unroll
    for (int rg = 0; rg < 2; rg++) {
#pragma unroll
      for (int t = 0; t < 4; t++)
#pragma unroll
        for (int r = 0; r < 4; r++) plds[w][q4 * 4 + r][t * 16 + c16] = f2bf_fast(s[rg][t][r]);
#pragma unroll
      for (int kl = 0; kl < 2; kl++)
        afrag[rg][kl] = *(const bf16x8*)(&plds[w][c16][kl * 32 + q4 * 8]);
    }
#pragma unroll
    for (int kl = 0; kl < 2; kl++)
#pragma unroll
      for (int nt = 0; nt < 3; nt++) {
        const u16* vrow = &vlds[cb][nt * 16 + c16][0];
        bf16x8 bv = *(const bf16x8*)(vrow + ((kl * 4 + q4) ^ r7) * 8);
#pragma unroll
        for (int rg = 0; rg < 2; rg++)
          o[rg][nt] = __builtin_amdgcn_mfma_f32_16x16x32_bf16(afrag[rg][kl], bv, o[rg][nt], 0, 0, 0);
      }
    __syncthreads();
  }

  // tail: keys 512..527 staged in buffer 0; only key 512 (c16==0) valid
  {
    f32x4 s4[2] = {{0, 0, 0, 0}, {0, 0, 0, 0}};
    const u16* krow = &klds[0][c16][0];
    bf16x8 k0 = *(const bf16x8*)(krow + (q4 ^ r7) * 8);
    bf16x8 k1 = *(const bf16x8*)(krow + ((q4 ^ r7) ^ 4) * 8);
#pragma unroll
    for (int rg = 0; rg < 2; rg++) {
      s4[rg] = __builtin_amdgcn_mfma_f32_16x16x32_bf16(aq[rg][0], k0, s4[rg], 0, 0, 0);
      s4[rg] = __builtin_amdgcn_mfma_f32_16x16x32_bf16(aq[rg][1], k1, s4[rg], 0, 0, 0);
    }
    bf16x8 afrag[2];
#pragma unroll
    for (int rg = 0; rg < 2; rg++) {
#pragma unroll
      for (int r = 0; r < 4; r++) {
        float e = (c16 == 0) ? __expf(s4[rg][r]) : 0.f;
        lsum[rg][r] += e;
        plds[w][q4 * 4 + r][c16] = f2bf_fast(e);
        plds[w][q4 * 4 + r][16 + c16] = 0;
      }
      afrag[rg] = *(const bf16x8*)(&plds[w][c16][q4 * 8]);
    }
#pragma unroll
    for (int nt = 0; nt < 3; nt++) {
      const u16* vrow = &vlds[0][nt * 16 + c16][0];
      bf16x8 bv = *(const bf16x8*)(vrow + (q4 ^ r7) * 8);
#pragma unroll
      for (int rg = 0; rg < 2; rg++)
        o[rg][nt] = __builtin_amdgcn_mfma_f32_16x16x32_bf16(afrag[rg], bv, o[rg][nt], 0, 0, 0);
    }
  }

  int b = bh >> 3, h = bh & 7;
#pragma unroll
  for (int rg = 0; rg < 2; rg++) {
    float inv[4];
#pragma unroll
    for (int r = 0; r < 4; r++) {
      float l = lsum[rg][r];
      l += __shfl_xor(l, 1);
      l += __shfl_xor(l, 2);
      l += __shfl_xor(l, 4);
      l += __shfl_xor(l, 8);
      inv[r] = 1.0f / l;
    }
#pragma unroll
    for (int nt = 0; nt < 3; nt++)
#pragma unroll
      for (int r = 0; r < 4; r++) {
        int n = n0 + rg * 16 + q4 * 4 + r;
        if (n < NTOK) outb[((size_t)(b * NTOK + n)) * 384 + h * 48 + nt * 16 + c16] = f2bf(o[rg][nt][r] * inv[r]);
      }
  }
}

extern "C" void kernel_launch(void* const* d_in, const int* in_sizes, int n_in,
                              void* d_out, int out_size, void* d_ws, size_t ws_size,
                              hipStream_t stream) {
  const float* x = (const float*)d_in[0];
  const float* q_w = (const float*)d_in[1];
  const float* kv_w = (const float*)d_in[2];
  const float* proj_w = (const float*)d_in[3];
  const float* proj_b = (const float*)d_in[4];
  const float* sr_w = (const float*)d_in[5];
  const float* sr_b = (const float*)d_in[6];
  const float* ln_g = (const float*)d_in[7];
  const float* ln_b = (const float*)d_in[8];
  float* out = (float*)d_out;

  u16* ws = (u16*)d_ws;
  u16* x_b = ws;                          // region used only as attn output now
  u16* qw_b = x_b + (size_t)ROWS_X * 384; // (unused, layout preserved)
  u16* kvw_b = qw_b + 147456;             // (unused, layout preserved)
  u16* pw_b = kvw_b + 294912;             // 147,456
  u16* q_b = pw_b + 147456;               // 32*4224*64      = 8,650,752
  u16* xln_b = q_b + (size_t)32 * NPAD_Q * 64;  // 4*544*384 = 835,584
  u16* k_b = xln_b + (size_t)4 * MPAD * 384;    // 32*640*64 = 1,310,720
  u16* vt_b = k_b + (size_t)32 * KPAD * 64;     // 32*48*640 = 983,040
  u16* attn_b = x_b;  // attn output lives in the old x_b region

  // No q_b memset (pads read as 0xAA bf16 = -3e-13; harmless per R11 audit).

  fused_qkv<<<KV_BLOCKS + Q_BLOCKS + PW_BLOCKS, 256, 0, stream>>>(
      x, q_w, kv_w, proj_w, sr_w, sr_b, ln_g, ln_b, q_b, k_b, vt_b, xln_b, pw_b);
  attn_kernel<<<dim3(32, 33), 256, 0, stream>>>(q_b, k_b, vt_b, attn_b);
  gemm_out<<<dim3(129, 3), 256, 0, stream>>>(attn_b, pw_b, out, proj_b);
}

// Round 7
// 175.998 us; speedup vs baseline: 2.5891x; 1.7503x over previous
//
#include <hip/hip_runtime.h>

typedef unsigned short u16;
typedef unsigned int u32;
typedef __bf16 bf16x8 __attribute__((ext_vector_type(8)));
typedef float f32x4 __attribute__((ext_vector_type(4)));

#define NTOK 4097
#define MTOK 513
#define MPAD 544     // 34*16 (xln row padding)
#define KPAD 640     // K/V padded
#define NPAD_Q 4224  // 33*128
#define ROWS_X 16512 // 129*128 (gemm block-staged rows)

__device__ __forceinline__ u16 f2bf(float f) {  // RNE (outputs)
  u32 u = __builtin_bit_cast(u32, f);
  u = u + 0x7FFFu + ((u >> 16) & 1u);
  return (u16)(u >> 16);
}
__device__ __forceinline__ u16 f2bf_fast(float f) {  // round-half-up (internal P)
  u32 u = __builtin_bit_cast(u32, f);
  return (u16)((u + 0x8000u) >> 16);
}

// async global->LDS DMA, 16B per lane; LDS dest = wave-uniform base + lane*16
__device__ __forceinline__ void gld16(const u16* g, u16* l) {
  __builtin_amdgcn_global_load_lds((const __attribute__((address_space(1))) u32*)g,
                                   (__attribute__((address_space(3))) u32*)l, 16, 0, 0);
}

#define NQW  147456
#define NKVW 294912
#define NPW  147456
#define GQW  (NQW / 8)
#define GKVW (NKVW / 8)
#define GPW  (NPW / 8)
#define GW   (GQW + GKVW + GPW)       // 73,728 8-elem groups (weights only)
#define SRLN_BLOCKS (4 * MTOK)        // 2052
#define CAST_BLOCKS 192               // 192*384 = 73,728 threads, 1 group each

// ---------------- pre-pass: sr_ln (blocks 0..2051) + weight casts (x cast eliminated) ----------------
__global__ void pre_kernel(const float* __restrict__ x, const float* __restrict__ qw,
                           const float* __restrict__ kvw, const float* __restrict__ pw,
                           const float* __restrict__ srw, const float* __restrict__ srb,
                           const float* __restrict__ lng, const float* __restrict__ lnb,
                           u16* __restrict__ qwb, u16* __restrict__ kvwb, u16* __restrict__ pwb,
                           u16* __restrict__ xln) {
  if (blockIdx.x < SRLN_BLOCKS) {
    // ---- sr_ln (R11-proven, verbatim) ----
    int c = threadIdx.x;  // 0..383
    int bm = blockIdx.x;
    int b = bm / MTOK, m = bm - b * MTOK;
    float v;
    if (m == 0) {
      v = x[(b * NTOK) * 384 + c];
    } else {
      int mo = m - 1;
      int oz = mo >> 6, oy = (mo >> 3) & 7, ox = mo & 7;
      float acc = srb[c];
#pragma unroll
      for (int dz = 0; dz < 2; dz++)
#pragma unroll
        for (int dy = 0; dy < 2; dy++)
#pragma unroll
          for (int dx = 0; dx < 2; dx++) {
            int tok = 1 + ((2 * oz + dz) * 256 + (2 * oy + dy) * 16 + (2 * ox + dx));
            acc += x[(b * NTOK + tok) * 384 + c] * srw[c * 8 + dz * 4 + dy * 2 + dx];
          }
      v = acc;
    }
    float s1 = v, s2 = v * v;
#pragma unroll
    for (int msk = 32; msk >= 1; msk >>= 1) {
      s1 += __shfl_xor(s1, msk);
      s2 += __shfl_xor(s2, msk);
    }
    __shared__ float r1[6], r2[6];
    int w = threadIdx.x >> 6, lane = threadIdx.x & 63;
    if (lane == 0) { r1[w] = s1; r2[w] = s2; }
    __syncthreads();
    float S1 = 0.f, S2 = 0.f;
#pragma unroll
    for (int i = 0; i < 6; i++) { S1 += r1[i]; S2 += r2[i]; }
    float mu = S1 * (1.0f / 384.0f);
    float var = S2 * (1.0f / 384.0f) - mu * mu;
    float y = (v - mu) * rsqrtf(var + 1e-5f) * lng[c] + lnb[c];
    xln[(b * MPAD + m) * 384 + c] = f2bf(y);
  } else {
    // ---- weight casts: 8 elems/thread, value-identical f2bf per element ----
    int idx = (blockIdx.x - SRLN_BLOCKS) * blockDim.x + threadIdx.x;
    int stride = (gridDim.x - SRLN_BLOCKS) * blockDim.x;
    for (int g = idx; g < GW; g += stride) {
      const float* s;
      u16* d;
      int off;
      if (g < GQW) { s = qw; d = qwb; off = g * 8; }
      else if (g < GQW + GKVW) { s = kvw; d = kvwb; off = (g - GQW) * 8; }
      else { s = pw; d = pwb; off = (g - GQW - GKVW) * 8; }
      float4 v0 = *(const float4*)(s + off);
      float4 v1 = *(const float4*)(s + off + 4);
      uint4 o;
      u16* p = (u16*)&o;
      p[0] = f2bf(v0.x); p[1] = f2bf(v0.y); p[2] = f2bf(v0.z); p[3] = f2bf(v0.w);
      p[4] = f2bf(v1.x); p[5] = f2bf(v1.y); p[6] = f2bf(v1.z); p[7] = f2bf(v1.w);
      *(uint4*)(d + off) = o;
    }
  }
}

// ---------------- GEMM core (R10-proven dbuf body, verbatim; kv-proj and out-proj) ----------------
__device__ __forceinline__ void gemm_core(u16* aLds, u16* bLds,
                                          const u16* __restrict__ A, const u16* __restrict__ W,
                                          int mode, size_t rbase, int c0,
                                          u16* __restrict__ o1, u16* __restrict__ o2,
                                          float* __restrict__ of, const float* __restrict__ bias) {
  int tid = threadIdx.x, w = tid >> 6, lane = tid & 63, q4 = lane >> 4, c16 = lane & 15;
  int wr = w >> 1, wc = w & 1;
  int x7 = c16 & 7;

  auto stageAB = [&](int kc, int buf) {
#pragma unroll
    for (int i = 0; i < 4; i++) {
      int s = (w * 4 + i) * 64 + lane;
      int row = s >> 3, chp = s & 7;
      int ch = chp ^ (row & 7);
      gld16(A + (rbase + row) * 384 + kc * 64 + ch * 8, &aLds[buf * 8192 + (w * 4 + i) * 512]);
    }
#pragma unroll
    for (int i = 0; i < 4; i++) {
      int s = (w * 4 + i) * 64 + lane;
      int row = s >> 3, chp = s & 7;
      int ch = chp ^ (row & 7);
      gld16(W + (size_t)(c0 + row) * 384 + kc * 64 + ch * 8, &bLds[buf * 8192 + (w * 4 + i) * 512]);
    }
  };
  stageAB(0, 0);
  __syncthreads();

  f32x4 acc[4][4];
#pragma unroll
  for (int mt = 0; mt < 4; mt++)
#pragma unroll
    for (int nt = 0; nt < 4; nt++) acc[mt][nt] = (f32x4){0, 0, 0, 0};

  for (int c = 0; c < 6; c++) {
    int cb = c & 1, nb = cb ^ 1;
    if (c < 5) stageAB(c + 1, nb);  // async; drains at this iter's end barrier
#pragma unroll
    for (int ks = 0; ks < 2; ks++) {
      bf16x8 af[4], bf[4];
#pragma unroll
      for (int mt = 0; mt < 4; mt++)
        af[mt] = *(const bf16x8*)(&aLds[cb * 8192 + (wr * 64 + mt * 16 + c16) * 64 + ((ks * 4 + q4) ^ x7) * 8]);
#pragma unroll
      for (int nt = 0; nt < 4; nt++)
        bf[nt] = *(const bf16x8*)(&bLds[cb * 8192 + (wc * 64 + nt * 16 + c16) * 64 + ((ks * 4 + q4) ^ x7) * 8]);
#pragma unroll
      for (int mt = 0; mt < 4; mt++)
#pragma unroll
        for (int nt = 0; nt < 4; nt++)
          acc[mt][nt] = __builtin_amdgcn_mfma_f32_16x16x32_bf16(af[mt], bf[nt], acc[mt][nt], 0, 0, 0);
    }
    __syncthreads();
  }

#pragma unroll
  for (int mt = 0; mt < 4; mt++)
#pragma unroll
    for (int nt = 0; nt < 4; nt++) {
      int col = c0 + wc * 64 + nt * 16 + c16;
#pragma unroll
      for (int r = 0; r < 4; r++) {
        int R = (int)rbase + wr * 64 + mt * 16 + q4 * 4 + r;
        float val = acc[mt][nt][r];
        if (mode == 1) {
          int b = R / MPAD;
          int m = R - b * MPAD;
          if (col < 384) {
            int h = col / 48, d = col - h * 48;
            o1[((size_t)(b * 8 + h) * KPAD + m) * 64 + d] = f2bf(val);
          } else {
            int c2 = col - 384;
            int h = c2 / 48, d = c2 - h * 48;
            o2[((size_t)(b * 8 + h) * 48 + d) * KPAD + m] = f2bf(val);
          }
        } else {
          if (R < 4 * NTOK) of[(size_t)R * 384 + col] = val + bias[col];
        }
      }
    }
}

// ---------------- GEMM core, f32-A variant (q-proj): reg-staged cast, half-split (R2-proven) ----
__device__ __forceinline__ void gemm_core_f32A(u16* aLds, u16* bLds,
                                               const float* __restrict__ X, const u16* __restrict__ W,
                                               size_t rbase, int c0, u16* __restrict__ o1) {
  int tid = threadIdx.x, w = tid >> 6, lane = tid & 63, q4 = lane >> 4, c16 = lane & 15;
  int wr = w >> 1, wc = w & 1;
  int x7 = c16 & 7;

  float4 ra[2][2];
  auto loadA2 = [&](int kc, int half) {
#pragma unroll
    for (int i = 0; i < 2; i++) {
      int idx2 = half * 2 + i;
      int s = (w * 4 + idx2) * 64 + lane;
      int row = s >> 3, chp = s & 7;
      int ch = chp ^ (row & 7);
      int ar = (int)rbase + row;
      if (ar > 16387) ar = 16387;  // clamp pad rows (outputs discarded: b>=4)
      const float* pa = X + (size_t)ar * 384 + kc * 64 + ch * 8;
      ra[i][0] = *(const float4*)pa;
      ra[i][1] = *(const float4*)(pa + 4);
    }
  };
  auto writeA2 = [&](int buf, int half) {
#pragma unroll
    for (int i = 0; i < 2; i++) {
      int idx2 = half * 2 + i;
      uint4 oa;
      u16* p = (u16*)&oa;
      p[0] = f2bf(ra[i][0].x); p[1] = f2bf(ra[i][0].y);
      p[2] = f2bf(ra[i][0].z); p[3] = f2bf(ra[i][0].w);
      p[4] = f2bf(ra[i][1].x); p[5] = f2bf(ra[i][1].y);
      p[6] = f2bf(ra[i][1].z); p[7] = f2bf(ra[i][1].w);
      *(uint4*)(&aLds[buf * 8192 + (w * 4 + idx2) * 512 + lane * 8]) = oa;
    }
  };
  auto stageB = [&](int kc, int buf) {
#pragma unroll
    for (int i = 0; i < 4; i++) {
      int s = (w * 4 + i) * 64 + lane;
      int row = s >> 3, chp = s & 7;
      int ch = chp ^ (row & 7);
      gld16(W + (size_t)(c0 + row) * 384 + kc * 64 + ch * 8, &bLds[buf * 8192 + (w * 4 + i) * 512]);
    }
  };

  loadA2(0, 0);
  stageB(0, 0);
  writeA2(0, 0);
  loadA2(0, 1);
  writeA2(0, 1);
  __syncthreads();

  f32x4 acc[4][4];
#pragma unroll
  for (int mt = 0; mt < 4; mt++)
#pragma unroll
    for (int nt = 0; nt < 4; nt++) acc[mt][nt] = (f32x4){0, 0, 0, 0};

  for (int c = 0; c < 6; c++) {
    int cb = c & 1, nb = cb ^ 1;
    if (c < 5) { loadA2(c + 1, 0); stageB(c + 1, nb); }
    // ks = 0
    {
      bf16x8 af[4], bf[4];
#pragma unroll
      for (int mt = 0; mt < 4; mt++)
        af[mt] = *(const bf16x8*)(&aLds[cb * 8192 + (wr * 64 + mt * 16 + c16) * 64 + ((0 + q4) ^ x7) * 8]);
#pragma unroll
      for (int nt = 0; nt < 4; nt++)
        bf[nt] = *(const bf16x8*)(&bLds[cb * 8192 + (wc * 64 + nt * 16 + c16) * 64 + ((0 + q4) ^ x7) * 8]);
#pragma unroll
      for (int mt = 0; mt < 4; mt++)
#pragma unroll
        for (int nt = 0; nt < 4; nt++)
          acc[mt][nt] = __builtin_amdgcn_mfma_f32_16x16x32_bf16(af[mt], bf[nt], acc[mt][nt], 0, 0, 0);
    }
    if (c < 5) { writeA2(nb, 0); loadA2(c + 1, 1); }
    // ks = 1
    {
      bf16x8 af[4], bf[4];
#pragma unroll
      for (int mt = 0; mt < 4; mt++)
        af[mt] = *(const bf16x8*)(&aLds[cb * 8192 + (wr * 64 + mt * 16 + c16) * 64 + ((4 + q4) ^ x7) * 8]);
#pragma unroll
      for (int nt = 0; nt < 4; nt++)
        bf[nt] = *(const bf16x8*)(&bLds[cb * 8192 + (wc * 64 + nt * 16 + c16) * 64 + ((4 + q4) ^ x7) * 8]);
#pragma unroll
      for (int mt = 0; mt < 4; mt++)
#pragma unroll
        for (int nt = 0; nt < 4; nt++)
          acc[mt][nt] = __builtin_amdgcn_mfma_f32_16x16x32_bf16(af[mt], bf[nt], acc[mt][nt], 0, 0, 0);
    }
    if (c < 5) writeA2(nb, 1);
    __syncthreads();
  }

#pragma unroll
  for (int mt = 0; mt < 4; mt++)
#pragma unroll
    for (int nt = 0; nt < 4; nt++) {
      int col = c0 + wc * 64 + nt * 16 + c16;
#pragma unroll
      for (int r = 0; r < 4; r++) {
        int R = (int)rbase + wr * 64 + mt * 16 + q4 * 4 + r;
        int b = R / NTOK;
        if (b >= 4) continue;
        int n = R - b * NTOK;
        int h = col / 48, d = col - h * 48;
        o1[((size_t)(b * 8 + h) * NPAD_Q + n) * 64 + d] =
            f2bf(acc[mt][nt][r] * 0.14433756729740643f);
      }
    }
}

// fused q-proj (blocks 0..386, f32 A) + kv-proj (blocks 387..488)
__global__ __launch_bounds__(256) void gemm_qkv(const float* __restrict__ x, const u16* __restrict__ qwb,
                                                const u16* __restrict__ xlnb, const u16* __restrict__ kvwb,
                                                u16* __restrict__ qb, u16* __restrict__ kb2,
                                                u16* __restrict__ vtb) {
  __shared__ __align__(16) u16 aLds[2 * 128 * 64];
  __shared__ __align__(16) u16 bLds[2 * 128 * 64];
  int bx = blockIdx.x;
  if (bx < 387) {
    gemm_core_f32A(aLds, bLds, x, qwb, (size_t)(bx % 129) * 128, (bx / 129) * 128, qb);
  } else {
    int i = bx - 387;
    gemm_core(aLds, bLds, xlnb, kvwb, 1, (size_t)(i % 17) * 128, (i / 17) * 128,
              kb2, vtb, nullptr, nullptr);
  }
}

// out-proj (mode 2)
__global__ __launch_bounds__(256) void gemm_out(const u16* __restrict__ A, const u16* __restrict__ W,
                                                float* __restrict__ of, const float* __restrict__ bias) {
  __shared__ __align__(16) u16 aLds[2 * 128 * 64];
  __shared__ __align__(16) u16 bLds[2 * 128 * 64];
  gemm_core(aLds, bLds, A, W, 2, (size_t)blockIdx.x * 128, blockIdx.y * 128,
            nullptr, nullptr, of, bias);
}

// ---------------- Attention (R11-proven body + s_setprio around MFMA clusters) ----------------
__global__ __launch_bounds__(256, 4) void attn_kernel(const u16* __restrict__ qb,
                                                      const u16* __restrict__ kb,
                                                      const u16* __restrict__ vt,
                                                      u16* __restrict__ outb) {
  __shared__ __align__(16) u16 klds[2][64][64];   // 16,384 B (unpadded: DMA dest)
  __shared__ __align__(16) u16 vlds[2][48][64];   // 12,288 B
  __shared__ __align__(16) u16 plds[4][16][76];   //  9,728 B (wave-private P scratch)
  int tid = threadIdx.x, w = tid >> 6, lane = tid & 63, q4 = lane >> 4, c16 = lane & 15;
  int bh = blockIdx.x;
  int n0 = blockIdx.y * 128 + w * 32;
  int r7 = c16 & 7;

  const uint4* qp = (const uint4*)(qb + ((size_t)bh * NPAD_Q + n0 + c16) * 64);
  bf16x8 aq[2][2];
#pragma unroll
  for (int rg = 0; rg < 2; rg++) {
    aq[rg][0] = __builtin_bit_cast(bf16x8, qp[rg * 128 + q4]);
    aq[rg][1] = __builtin_bit_cast(bf16x8, qp[rg * 128 + 4 + q4]);
  }

  const u16* kbase = kb + (size_t)bh * KPAD * 64;
  const u16* vbase = vt + (size_t)bh * 48 * KPAD;

  auto stage = [&](int cn, int buf) {
#pragma unroll
    for (int i = 0; i < 2; i++) {
      int s = (w * 2 + i) * 64 + lane;
      int row = s >> 3, chp = s & 7;
      int ch = chp ^ (row & 7);
      gld16(kbase + (size_t)(cn * 64 + row) * 64 + ch * 8, &klds[buf][(w * 2 + i) * 8][0]);
    }
#pragma unroll
    for (int i = 0; i < 2; i++) {
      int blk = w * 2 + i;
      if (blk < 6) {
        int s = blk * 64 + lane;
        int row = s >> 3, chp = s & 7;
        int ch = chp ^ (row & 7);
        gld16(vbase + (size_t)row * KPAD + cn * 64 + ch * 8, &vlds[buf][blk * 8][0]);
      }
    }
  };

  stage(0, 0);
  __syncthreads();

  f32x4 o[2][3];
  float lsum[2][4];
#pragma unroll
  for (int rg = 0; rg < 2; rg++) {
#pragma unroll
    for (int nt = 0; nt < 3; nt++) o[rg][nt] = (f32x4){0, 0, 0, 0};
#pragma unroll
    for (int r = 0; r < 4; r++) lsum[rg][r] = 0.f;
  }

  for (int c = 0; c < 8; c++) {
    int cb = c & 1, nb = cb ^ 1;
    stage(c + 1, nb);  // c=7 stages the tail chunk (keys 512..575) into buffer 0

    f32x4 s[2][4];
#pragma unroll
    for (int rg = 0; rg < 2; rg++)
#pragma unroll
      for (int t = 0; t < 4; t++) s[rg][t] = (f32x4){0, 0, 0, 0};
    __builtin_amdgcn_s_setprio(1);
#pragma unroll
    for (int t = 0; t < 4; t++) {
      const u16* krow = &klds[cb][t * 16 + c16][0];
      bf16x8 k0 = *(const bf16x8*)(krow + (q4 ^ r7) * 8);
      bf16x8 k1 = *(const bf16x8*)(krow + ((q4 ^ r7) ^ 4) * 8);
#pragma unroll
      for (int rg = 0; rg < 2; rg++) {
        s[rg][t] = __builtin_amdgcn_mfma_f32_16x16x32_bf16(aq[rg][0], k0, s[rg][t], 0, 0, 0);
        s[rg][t] = __builtin_amdgcn_mfma_f32_16x16x32_bf16(aq[rg][1], k1, s[rg][t], 0, 0, 0);
      }
    }
    __builtin_amdgcn_s_setprio(0);
#pragma unroll
    for (int rg = 0; rg < 2; rg++)
#pragma unroll
      for (int t = 0; t < 4; t++)
#pragma unroll
        for (int r = 0; r < 4; r++) {
          float e = __expf(s[rg][t][r]);
          s[rg][t][r] = e;
          lsum[rg][r] += e;
        }
    bf16x8 afrag[2][2];
#pragma unroll
    for (int rg = 0; rg < 2; rg++) {
#pragma unroll
      for (int t = 0; t < 4; t++)
#pragma unroll
        for (int r = 0; r < 4; r++) plds[w][q4 * 4 + r][t * 16 + c16] = f2bf_fast(s[rg][t][r]);
#pragma unroll
      for (int kl = 0; kl < 2; kl++)
        afrag[rg][kl] = *(const bf16x8*)(&plds[w][c16][kl * 32 + q4 * 8]);
    }
    __builtin_amdgcn_s_setprio(1);
#pragma unroll
    for (int kl = 0; kl < 2; kl++)
#pragma unroll
      for (int nt = 0; nt < 3; nt++) {
        const u16* vrow = &vlds[cb][nt * 16 + c16][0];
        bf16x8 bv = *(const bf16x8*)(vrow + ((kl * 4 + q4) ^ r7) * 8);
#pragma unroll
        for (int rg = 0; rg < 2; rg++)
          o[rg][nt] = __builtin_amdgcn_mfma_f32_16x16x32_bf16(afrag[rg][kl], bv, o[rg][nt], 0, 0, 0);
      }
    __builtin_amdgcn_s_setprio(0);
    __syncthreads();
  }

  // tail: keys 512..527 staged in buffer 0; only key 512 (c16==0) valid
  {
    f32x4 s4[2] = {{0, 0, 0, 0}, {0, 0, 0, 0}};
    const u16* krow = &klds[0][c16][0];
    bf16x8 k0 = *(const bf16x8*)(krow + (q4 ^ r7) * 8);
    bf16x8 k1 = *(const bf16x8*)(krow + ((q4 ^ r7) ^ 4) * 8);
#pragma unroll
    for (int rg = 0; rg < 2; rg++) {
      s4[rg] = __builtin_amdgcn_mfma_f32_16x16x32_bf16(aq[rg][0], k0, s4[rg], 0, 0, 0);
      s4[rg] = __builtin_amdgcn_mfma_f32_16x16x32_bf16(aq[rg][1], k1, s4[rg], 0, 0, 0);
    }
    bf16x8 afrag[2];
#pragma unroll
    for (int rg = 0; rg < 2; rg++) {
#pragma unroll
      for (int r = 0; r < 4; r++) {
        float e = (c16 == 0) ? __expf(s4[rg][r]) : 0.f;
        lsum[rg][r] += e;
        plds[w][q4 * 4 + r][c16] = f2bf_fast(e);
        plds[w][q4 * 4 + r][16 + c16] = 0;
      }
      afrag[rg] = *(const bf16x8*)(&plds[w][c16][q4 * 8]);
    }
#pragma unroll
    for (int nt = 0; nt < 3; nt++) {
      const u16* vrow = &vlds[0][nt * 16 + c16][0];
      bf16x8 bv = *(const bf16x8*)(vrow + (q4 ^ r7) * 8);
#pragma unroll
      for (int rg = 0; rg < 2; rg++)
        o[rg][nt] = __builtin_amdgcn_mfma_f32_16x16x32_bf16(afrag[rg], bv, o[rg][nt], 0, 0, 0);
    }
  }

  int b = bh >> 3, h = bh & 7;
#pragma unroll
  for (int rg = 0; rg < 2; rg++) {
    float inv[4];
#pragma unroll
    for (int r = 0; r < 4; r++) {
      float l = lsum[rg][r];
      l += __shfl_xor(l, 1);
      l += __shfl_xor(l, 2);
      l += __shfl_xor(l, 4);
      l += __shfl_xor(l, 8);
      inv[r] = 1.0f / l;
    }
#pragma unroll
    for (int nt = 0; nt < 3; nt++)
#pragma unroll
      for (int r = 0; r < 4; r++) {
        int n = n0 + rg * 16 + q4 * 4 + r;
        if (n < NTOK) outb[((size_t)(b * NTOK + n)) * 384 + h * 48 + nt * 16 + c16] = f2bf(o[rg][nt][r] * inv[r]);
      }
  }
}

extern "C" void kernel_launch(void* const* d_in, const int* in_sizes, int n_in,
                              void* d_out, int out_size, void* d_ws, size_t ws_size,
                              hipStream_t stream) {
  const float* x = (const float*)d_in[0];
  const float* q_w = (const float*)d_in[1];
  const float* kv_w = (const float*)d_in[2];
  const float* proj_w = (const float*)d_in[3];
  const float* proj_b = (const float*)d_in[4];
  const float* sr_w = (const float*)d_in[5];
  const float* sr_b = (const float*)d_in[6];
  const float* ln_g = (const float*)d_in[7];
  const float* ln_b = (const float*)d_in[8];
  float* out = (float*)d_out;

  u16* ws = (u16*)d_ws;
  u16* x_b = ws;                          // region reused for attn output (x cast eliminated)
  u16* qw_b = x_b + (size_t)ROWS_X * 384; // 147,456
  u16* kvw_b = qw_b + 147456;             // 294,912
  u16* pw_b = kvw_b + 294912;             // 147,456
  u16* q_b = pw_b + 147456;               // 32*4224*64      = 8,650,752
  u16* xln_b = q_b + (size_t)32 * NPAD_Q * 64;  // 4*544*384 = 835,584
  u16* k_b = xln_b + (size_t)4 * MPAD * 384;    // 32*640*64 = 1,310,720
  u16* vt_b = k_b + (size_t)32 * KPAD * 64;     // 32*48*640 = 983,040
  u16* attn_b = x_b;  // attn output lives in the old x_b region

  // No q_b memset (pads read as 0xAA bf16 = -3e-13; harmless per R11 audit).

  pre_kernel<<<SRLN_BLOCKS + CAST_BLOCKS, 384, 0, stream>>>(x, q_w, kv_w, proj_w, sr_w, sr_b,
                                                            ln_g, ln_b, qw_b, kvw_b, pw_b, xln_b);
  gemm_qkv<<<489, 256, 0, stream>>>(x, qw_b, xln_b, kvw_b, q_b, k_b, vt_b);
  attn_kernel<<<dim3(32, 33), 256, 0, stream>>>(q_b, k_b, vt_b, attn_b);
  gemm_out<<<dim3(129, 3), 256, 0, stream>>>(attn_b, pw_b, out, proj_b);
}

// Round 8
// 164.668 us; speedup vs baseline: 2.7673x; 1.0688x over previous
//
#include <hip/hip_runtime.h>

typedef unsigned short u16;
typedef unsigned int u32;
typedef __bf16 bf16x8 __attribute__((ext_vector_type(8)));
typedef float f32x4 __attribute__((ext_vector_type(4)));

#define NTOK 4097
#define MTOK 513
#define MPAD 544     // 34*16 (xln row padding)
#define KPAD 640     // K/V padded
#define NPAD_Q 4224  // 33*128
#define ROWS_X 16512 // 129*128 (gemm block-staged rows)

__device__ __forceinline__ u16 f2bf(float f) {  // RNE (outputs)
  u32 u = __builtin_bit_cast(u32, f);
  u = u + 0x7FFFu + ((u >> 16) & 1u);
  return (u16)(u >> 16);
}
__device__ __forceinline__ u16 f2bf_fast(float f) {  // round-half-up (internal P)
  u32 u = __builtin_bit_cast(u32, f);
  return (u16)((u + 0x8000u) >> 16);
}

// bare v_exp_f32 (2^x). q-scale carries log2(e), so exp(S) == fexp2(S') with no v_mul.
__device__ __forceinline__ float fexp2(float x) {
#if __has_builtin(__builtin_amdgcn_exp2f)
  return __builtin_amdgcn_exp2f(x);
#else
  float r;
  asm("v_exp_f32 %0, %1" : "=v"(r) : "v"(x));
  return r;
#endif
}

// async global->LDS DMA, 16B per lane; LDS dest = wave-uniform base + lane*16
__device__ __forceinline__ void gld16(const u16* g, u16* l) {
  __builtin_amdgcn_global_load_lds((const __attribute__((address_space(1))) u32*)g,
                                   (__attribute__((address_space(3))) u32*)l, 16, 0, 0);
}

// XCD-coherent triplet remap: the 3 tiles sharing an A row-panel get ids differing by 8
// (same XCD under id%8 round-robin) -> panel is an L2 hit for 2 of 3. Bijective on 0..386.
__device__ __forceinline__ void remap387(int bx, int& row, int& colg) {
  if (bx < 384) {
    int chunk = bx / 24, rem = bx % 24;
    colg = rem >> 3;
    row = chunk * 8 + (rem & 7);
  } else {
    row = 128;
    colg = bx - 384;
  }
}

#define NQW  147456
#define NKVW 294912
#define NPW  147456
#define GQW  (NQW / 8)
#define GKVW (NKVW / 8)
#define GPW  (NPW / 8)
#define GW   (GQW + GKVW + GPW)       // 73,728 8-elem groups (weights only)
#define SRLN_BLOCKS (4 * MTOK)        // 2052
#define CAST_BLOCKS 192               // 192*384 = 73,728 threads, 1 group each

// ---------------- pre-pass: sr_ln (blocks 0..2051) + weight casts (x cast eliminated) ----------------
__global__ void pre_kernel(const float* __restrict__ x, const float* __restrict__ qw,
                           const float* __restrict__ kvw, const float* __restrict__ pw,
                           const float* __restrict__ srw, const float* __restrict__ srb,
                           const float* __restrict__ lng, const float* __restrict__ lnb,
                           u16* __restrict__ qwb, u16* __restrict__ kvwb, u16* __restrict__ pwb,
                           u16* __restrict__ xln) {
  if (blockIdx.x < SRLN_BLOCKS) {
    // ---- sr_ln (R11-proven, verbatim) ----
    int c = threadIdx.x;  // 0..383
    int bm = blockIdx.x;
    int b = bm / MTOK, m = bm - b * MTOK;
    float v;
    if (m == 0) {
      v = x[(b * NTOK) * 384 + c];
    } else {
      int mo = m - 1;
      int oz = mo >> 6, oy = (mo >> 3) & 7, ox = mo & 7;
      float acc = srb[c];
#pragma unroll
      for (int dz = 0; dz < 2; dz++)
#pragma unroll
        for (int dy = 0; dy < 2; dy++)
#pragma unroll
          for (int dx = 0; dx < 2; dx++) {
            int tok = 1 + ((2 * oz + dz) * 256 + (2 * oy + dy) * 16 + (2 * ox + dx));
            acc += x[(b * NTOK + tok) * 384 + c] * srw[c * 8 + dz * 4 + dy * 2 + dx];
          }
      v = acc;
    }
    float s1 = v, s2 = v * v;
#pragma unroll
    for (int msk = 32; msk >= 1; msk >>= 1) {
      s1 += __shfl_xor(s1, msk);
      s2 += __shfl_xor(s2, msk);
    }
    __shared__ float r1[6], r2[6];
    int w = threadIdx.x >> 6, lane = threadIdx.x & 63;
    if (lane == 0) { r1[w] = s1; r2[w] = s2; }
    __syncthreads();
    float S1 = 0.f, S2 = 0.f;
#pragma unroll
    for (int i = 0; i < 6; i++) { S1 += r1[i]; S2 += r2[i]; }
    float mu = S1 * (1.0f / 384.0f);
    float var = S2 * (1.0f / 384.0f) - mu * mu;
    float y = (v - mu) * rsqrtf(var + 1e-5f) * lng[c] + lnb[c];
    xln[(b * MPAD + m) * 384 + c] = f2bf(y);
  } else {
    // ---- weight casts: 8 elems/thread, value-identical f2bf per element ----
    int idx = (blockIdx.x - SRLN_BLOCKS) * blockDim.x + threadIdx.x;
    int stride = (gridDim.x - SRLN_BLOCKS) * blockDim.x;
    for (int g = idx; g < GW; g += stride) {
      const float* s;
      u16* d;
      int off;
      if (g < GQW) { s = qw; d = qwb; off = g * 8; }
      else if (g < GQW + GKVW) { s = kvw; d = kvwb; off = (g - GQW) * 8; }
      else { s = pw; d = pwb; off = (g - GQW - GKVW) * 8; }
      float4 v0 = *(const float4*)(s + off);
      float4 v1 = *(const float4*)(s + off + 4);
      uint4 o;
      u16* p = (u16*)&o;
      p[0] = f2bf(v0.x); p[1] = f2bf(v0.y); p[2] = f2bf(v0.z); p[3] = f2bf(v0.w);
      p[4] = f2bf(v1.x); p[5] = f2bf(v1.y); p[6] = f2bf(v1.z); p[7] = f2bf(v1.w);
      *(uint4*)(d + off) = o;
    }
  }
}

// ---------------- GEMM core (R10-proven dbuf body, verbatim; kv-proj and out-proj) ----------------
__device__ __forceinline__ void gemm_core(u16* aLds, u16* bLds,
                                          const u16* __restrict__ A, const u16* __restrict__ W,
                                          int mode, size_t rbase, int c0,
                                          u16* __restrict__ o1, u16* __restrict__ o2,
                                          float* __restrict__ of, const float* __restrict__ bias) {
  int tid = threadIdx.x, w = tid >> 6, lane = tid & 63, q4 = lane >> 4, c16 = lane & 15;
  int wr = w >> 1, wc = w & 1;
  int x7 = c16 & 7;

  auto stageAB = [&](int kc, int buf) {
#pragma unroll
    for (int i = 0; i < 4; i++) {
      int s = (w * 4 + i) * 64 + lane;
      int row = s >> 3, chp = s & 7;
      int ch = chp ^ (row & 7);
      gld16(A + (rbase + row) * 384 + kc * 64 + ch * 8, &aLds[buf * 8192 + (w * 4 + i) * 512]);
    }
#pragma unroll
    for (int i = 0; i < 4; i++) {
      int s = (w * 4 + i) * 64 + lane;
      int row = s >> 3, chp = s & 7;
      int ch = chp ^ (row & 7);
      gld16(W + (size_t)(c0 + row) * 384 + kc * 64 + ch * 8, &bLds[buf * 8192 + (w * 4 + i) * 512]);
    }
  };
  stageAB(0, 0);
  __syncthreads();

  f32x4 acc[4][4];
#pragma unroll
  for (int mt = 0; mt < 4; mt++)
#pragma unroll
    for (int nt = 0; nt < 4; nt++) acc[mt][nt] = (f32x4){0, 0, 0, 0};

  for (int c = 0; c < 6; c++) {
    int cb = c & 1, nb = cb ^ 1;
    if (c < 5) stageAB(c + 1, nb);  // async; drains at this iter's end barrier
#pragma unroll
    for (int ks = 0; ks < 2; ks++) {
      bf16x8 af[4], bf[4];
#pragma unroll
      for (int mt = 0; mt < 4; mt++)
        af[mt] = *(const bf16x8*)(&aLds[cb * 8192 + (wr * 64 + mt * 16 + c16) * 64 + ((ks * 4 + q4) ^ x7) * 8]);
#pragma unroll
      for (int nt = 0; nt < 4; nt++)
        bf[nt] = *(const bf16x8*)(&bLds[cb * 8192 + (wc * 64 + nt * 16 + c16) * 64 + ((ks * 4 + q4) ^ x7) * 8]);
#pragma unroll
      for (int mt = 0; mt < 4; mt++)
#pragma unroll
        for (int nt = 0; nt < 4; nt++)
          acc[mt][nt] = __builtin_amdgcn_mfma_f32_16x16x32_bf16(af[mt], bf[nt], acc[mt][nt], 0, 0, 0);
    }
    __syncthreads();
  }

#pragma unroll
  for (int mt = 0; mt < 4; mt++)
#pragma unroll
    for (int nt = 0; nt < 4; nt++) {
      int col = c0 + wc * 64 + nt * 16 + c16;
#pragma unroll
      for (int r = 0; r < 4; r++) {
        int R = (int)rbase + wr * 64 + mt * 16 + q4 * 4 + r;
        float val = acc[mt][nt][r];
        if (mode == 1) {
          int b = R / MPAD;
          int m = R - b * MPAD;
          if (col < 384) {
            int h = col / 48, d = col - h * 48;
            o1[((size_t)(b * 8 + h) * KPAD + m) * 64 + d] = f2bf(val);
          } else {
            int c2 = col - 384;
            int h = c2 / 48, d = c2 - h * 48;
            o2[((size_t)(b * 8 + h) * 48 + d) * KPAD + m] = f2bf(val);
          }
        } else {
          if (R < 4 * NTOK) of[(size_t)R * 384 + col] = val + bias[col];
        }
      }
    }
}

// ---------------- GEMM core, f32-A variant (q-proj): reg-staged cast, half-split (R2-proven) ----
__device__ __forceinline__ void gemm_core_f32A(u16* aLds, u16* bLds,
                                               const float* __restrict__ X, const u16* __restrict__ W,
                                               size_t rbase, int c0, u16* __restrict__ o1) {
  int tid = threadIdx.x, w = tid >> 6, lane = tid & 63, q4 = lane >> 4, c16 = lane & 15;
  int wr = w >> 1, wc = w & 1;
  int x7 = c16 & 7;

  float4 ra[2][2];
  auto loadA2 = [&](int kc, int half) {
#pragma unroll
    for (int i = 0; i < 2; i++) {
      int idx2 = half * 2 + i;
      int s = (w * 4 + idx2) * 64 + lane;
      int row = s >> 3, chp = s & 7;
      int ch = chp ^ (row & 7);
      int ar = (int)rbase + row;
      if (ar > 16387) ar = 16387;  // clamp pad rows (outputs discarded: b>=4)
      const float* pa = X + (size_t)ar * 384 + kc * 64 + ch * 8;
      ra[i][0] = *(const float4*)pa;
      ra[i][1] = *(const float4*)(pa + 4);
    }
  };
  auto writeA2 = [&](int buf, int half) {
#pragma unroll
    for (int i = 0; i < 2; i++) {
      int idx2 = half * 2 + i;
      uint4 oa;
      u16* p = (u16*)&oa;
      p[0] = f2bf(ra[i][0].x); p[1] = f2bf(ra[i][0].y);
      p[2] = f2bf(ra[i][0].z); p[3] = f2bf(ra[i][0].w);
      p[4] = f2bf(ra[i][1].x); p[5] = f2bf(ra[i][1].y);
      p[6] = f2bf(ra[i][1].z); p[7] = f2bf(ra[i][1].w);
      *(uint4*)(&aLds[buf * 8192 + (w * 4 + idx2) * 512 + lane * 8]) = oa;
    }
  };
  auto stageB = [&](int kc, int buf) {
#pragma unroll
    for (int i = 0; i < 4; i++) {
      int s = (w * 4 + i) * 64 + lane;
      int row = s >> 3, chp = s & 7;
      int ch = chp ^ (row & 7);
      gld16(W + (size_t)(c0 + row) * 384 + kc * 64 + ch * 8, &bLds[buf * 8192 + (w * 4 + i) * 512]);
    }
  };

  loadA2(0, 0);
  stageB(0, 0);
  writeA2(0, 0);
  loadA2(0, 1);
  writeA2(0, 1);
  __syncthreads();

  f32x4 acc[4][4];
#pragma unroll
  for (int mt = 0; mt < 4; mt++)
#pragma unroll
    for (int nt = 0; nt < 4; nt++) acc[mt][nt] = (f32x4){0, 0, 0, 0};

  for (int c = 0; c < 6; c++) {
    int cb = c & 1, nb = cb ^ 1;
    if (c < 5) { loadA2(c + 1, 0); stageB(c + 1, nb); }
    // ks = 0
    {
      bf16x8 af[4], bf[4];
#pragma unroll
      for (int mt = 0; mt < 4; mt++)
        af[mt] = *(const bf16x8*)(&aLds[cb * 8192 + (wr * 64 + mt * 16 + c16) * 64 + ((0 + q4) ^ x7) * 8]);
#pragma unroll
      for (int nt = 0; nt < 4; nt++)
        bf[nt] = *(const bf16x8*)(&bLds[cb * 8192 + (wc * 64 + nt * 16 + c16) * 64 + ((0 + q4) ^ x7) * 8]);
#pragma unroll
      for (int mt = 0; mt < 4; mt++)
#pragma unroll
        for (int nt = 0; nt < 4; nt++)
          acc[mt][nt] = __builtin_amdgcn_mfma_f32_16x16x32_bf16(af[mt], bf[nt], acc[mt][nt], 0, 0, 0);
    }
    if (c < 5) { writeA2(nb, 0); loadA2(c + 1, 1); }
    // ks = 1
    {
      bf16x8 af[4], bf[4];
#pragma unroll
      for (int mt = 0; mt < 4; mt++)
        af[mt] = *(const bf16x8*)(&aLds[cb * 8192 + (wr * 64 + mt * 16 + c16) * 64 + ((4 + q4) ^ x7) * 8]);
#pragma unroll
      for (int nt = 0; nt < 4; nt++)
        bf[nt] = *(const bf16x8*)(&bLds[cb * 8192 + (wc * 64 + nt * 16 + c16) * 64 + ((4 + q4) ^ x7) * 8]);
#pragma unroll
      for (int mt = 0; mt < 4; mt++)
#pragma unroll
        for (int nt = 0; nt < 4; nt++)
          acc[mt][nt] = __builtin_amdgcn_mfma_f32_16x16x32_bf16(af[mt], bf[nt], acc[mt][nt], 0, 0, 0);
    }
    if (c < 5) writeA2(nb, 1);
    __syncthreads();
  }

#pragma unroll
  for (int mt = 0; mt < 4; mt++)
#pragma unroll
    for (int nt = 0; nt < 4; nt++) {
      int col = c0 + wc * 64 + nt * 16 + c16;
#pragma unroll
      for (int r = 0; r < 4; r++) {
        int R = (int)rbase + wr * 64 + mt * 16 + q4 * 4 + r;
        int b = R / NTOK;
        if (b >= 4) continue;
        int n = R - b * NTOK;
        int h = col / 48, d = col - h * 48;
        // scale = 48^-0.5 * log2(e): attn then uses bare v_exp_f32 (exp2)
        o1[((size_t)(b * 8 + h) * NPAD_Q + n) * 64 + d] =
            f2bf(acc[mt][nt][r] * (0.14433756729740643f * 1.4426950408889634f));
      }
    }
}

// fused q-proj (blocks 0..386, f32 A, XCD-triplet remap) + kv-proj (blocks 387..488)
__global__ __launch_bounds__(256) void gemm_qkv(const float* __restrict__ x, const u16* __restrict__ qwb,
                                                const u16* __restrict__ xlnb, const u16* __restrict__ kvwb,
                                                u16* __restrict__ qb, u16* __restrict__ kb2,
                                                u16* __restrict__ vtb) {
  __shared__ __align__(16) u16 aLds[2 * 128 * 64];
  __shared__ __align__(16) u16 bLds[2 * 128 * 64];
  int bx = blockIdx.x;
  if (bx < 387) {
    int row, colg;
    remap387(bx, row, colg);
    gemm_core_f32A(aLds, bLds, x, qwb, (size_t)row * 128, colg * 128, qb);
  } else {
    int i = bx - 387;
    gemm_core(aLds, bLds, xlnb, kvwb, 1, (size_t)(i % 17) * 128, (i / 17) * 128,
              kb2, vtb, nullptr, nullptr);
  }
}

// out-proj (mode 2, XCD-triplet remap)
__global__ __launch_bounds__(256) void gemm_out(const u16* __restrict__ A, const u16* __restrict__ W,
                                                float* __restrict__ of, const float* __restrict__ bias) {
  __shared__ __align__(16) u16 aLds[2 * 128 * 64];
  __shared__ __align__(16) u16 bLds[2 * 128 * 64];
  int row, colg;
  remap387(blockIdx.x, row, colg);
  gemm_core(aLds, bLds, A, W, 2, (size_t)row * 128, colg * 128,
            nullptr, nullptr, of, bias);
}

// ---------------- Attention (R7-proven body; __expf -> bare exp2, scale pre-folded) ----------------
__global__ __launch_bounds__(256, 4) void attn_kernel(const u16* __restrict__ qb,
                                                      const u16* __restrict__ kb,
                                                      const u16* __restrict__ vt,
                                                      u16* __restrict__ outb) {
  __shared__ __align__(16) u16 klds[2][64][64];   // 16,384 B (unpadded: DMA dest)
  __shared__ __align__(16) u16 vlds[2][48][64];   // 12,288 B
  __shared__ __align__(16) u16 plds[4][16][76];   //  9,728 B (wave-private P scratch)
  int tid = threadIdx.x, w = tid >> 6, lane = tid & 63, q4 = lane >> 4, c16 = lane & 15;
  int bh = blockIdx.x;
  int n0 = blockIdx.y * 128 + w * 32;
  int r7 = c16 & 7;

  const uint4* qp = (const uint4*)(qb + ((size_t)bh * NPAD_Q + n0 + c16) * 64);
  bf16x8 aq[2][2];
#pragma unroll
  for (int rg = 0; rg < 2; rg++) {
    aq[rg][0] = __builtin_bit_cast(bf16x8, qp[rg * 128 + q4]);
    aq[rg][1] = __builtin_bit_cast(bf16x8, qp[rg * 128 + 4 + q4]);
  }

  const u16* kbase = kb + (size_t)bh * KPAD * 64;
  const u16* vbase = vt + (size_t)bh * 48 * KPAD;

  auto stage = [&](int cn, int buf) {
#pragma unroll
    for (int i = 0; i < 2; i++) {
      int s = (w * 2 + i) * 64 + lane;
      int row = s >> 3, chp = s & 7;
      int ch = chp ^ (row & 7);
      gld16(kbase + (size_t)(cn * 64 + row) * 64 + ch * 8, &klds[buf][(w * 2 + i) * 8][0]);
    }
#pragma unroll
    for (int i = 0; i < 2; i++) {
      int blk = w * 2 + i;
      if (blk < 6) {
        int s = blk * 64 + lane;
        int row = s >> 3, chp = s & 7;
        int ch = chp ^ (row & 7);
        gld16(vbase + (size_t)row * KPAD + cn * 64 + ch * 8, &vlds[buf][blk * 8][0]);
      }
    }
  };

  stage(0, 0);
  __syncthreads();

  f32x4 o[2][3];
  float lsum[2][4];
#pragma unroll
  for (int rg = 0; rg < 2; rg++) {
#pragma unroll
    for (int nt = 0; nt < 3; nt++) o[rg][nt] = (f32x4){0, 0, 0, 0};
#pragma unroll
    for (int r = 0; r < 4; r++) lsum[rg][r] = 0.f;
  }

  for (int c = 0; c < 8; c++) {
    int cb = c & 1, nb = cb ^ 1;
    stage(c + 1, nb);  // c=7 stages the tail chunk (keys 512..575) into buffer 0

    f32x4 s[2][4];
#pragma unroll
    for (int rg = 0; rg < 2; rg++)
#pragma unroll
      for (int t = 0; t < 4; t++) s[rg][t] = (f32x4){0, 0, 0, 0};
    __builtin_amdgcn_s_setprio(1);
#pragma unroll
    for (int t = 0; t < 4; t++) {
      const u16* krow = &klds[cb][t * 16 + c16][0];
      bf16x8 k0 = *(const bf16x8*)(krow + (q4 ^ r7) * 8);
      bf16x8 k1 = *(const bf16x8*)(krow + ((q4 ^ r7) ^ 4) * 8);
#pragma unroll
      for (int rg = 0; rg < 2; rg++) {
        s[rg][t] = __builtin_amdgcn_mfma_f32_16x16x32_bf16(aq[rg][0], k0, s[rg][t], 0, 0, 0);
        s[rg][t] = __builtin_amdgcn_mfma_f32_16x16x32_bf16(aq[rg][1], k1, s[rg][t], 0, 0, 0);
      }
    }
    __builtin_amdgcn_s_setprio(0);
#pragma unroll
    for (int rg = 0; rg < 2; rg++)
#pragma unroll
      for (int t = 0; t < 4; t++)
#pragma unroll
        for (int r = 0; r < 4; r++) {
          float e = fexp2(s[rg][t][r]);
          s[rg][t][r] = e;
          lsum[rg][r] += e;
        }
    bf16x8 afrag[2][2];
#pragma unroll
    for (int rg = 0; rg < 2; rg++) {
#pragma unroll
      for (int t = 0; t < 4; t++)
#pragma unroll
        for (int r = 0; r < 4; r++) plds[w][q4 * 4 + r][t * 16 + c16] = f2bf_fast(s[rg][t][r]);
#pragma unroll
      for (int kl = 0; kl < 2; kl++)
        afrag[rg][kl] = *(const bf16x8*)(&plds[w][c16][kl * 32 + q4 * 8]);
    }
    __builtin_amdgcn_s_setprio(1);
#pragma unroll
    for (int kl = 0; kl < 2; kl++)
#pragma unroll
      for (int nt = 0; nt < 3; nt++) {
        const u16* vrow = &vlds[cb][nt * 16 + c16][0];
        bf16x8 bv = *(const bf16x8*)(vrow + ((kl * 4 + q4) ^ r7) * 8);
#pragma unroll
        for (int rg = 0; rg < 2; rg++)
          o[rg][nt] = __builtin_amdgcn_mfma_f32_16x16x32_bf16(afrag[rg][kl], bv, o[rg][nt], 0, 0, 0);
      }
    __builtin_amdgcn_s_setprio(0);
    __syncthreads();
  }

  // tail: keys 512..527 staged in buffer 0; only key 512 (c16==0) valid
  {
    f32x4 s4[2] = {{0, 0, 0, 0}, {0, 0, 0, 0}};
    const u16* krow = &klds[0][c16][0];
    bf16x8 k0 = *(const bf16x8*)(krow + (q4 ^ r7) * 8);
    bf16x8 k1 = *(const bf16x8*)(krow + ((q4 ^ r7) ^ 4) * 8);
#pragma unroll
    for (int rg = 0; rg < 2; rg++) {
      s4[rg] = __builtin_amdgcn_mfma_f32_16x16x32_bf16(aq[rg][0], k0, s4[rg], 0, 0, 0);
      s4[rg] = __builtin_amdgcn_mfma_f32_16x16x32_bf16(aq[rg][1], k1, s4[rg], 0, 0, 0);
    }
    bf16x8 afrag[2];
#pragma unroll
    for (int rg = 0; rg < 2; rg++) {
#pragma unroll
      for (int r = 0; r < 4; r++) {
        float e = (c16 == 0) ? fexp2(s4[rg][r]) : 0.f;
        lsum[rg][r] += e;
        plds[w][q4 * 4 + r][c16] = f2bf_fast(e);
        plds[w][q4 * 4 + r][16 + c16] = 0;
      }
      afrag[rg] = *(const bf16x8*)(&plds[w][c16][q4 * 8]);
    }
#pragma unroll
    for (int nt = 0; nt < 3; nt++) {
      const u16* vrow = &vlds[0][nt * 16 + c16][0];
      bf16x8 bv = *(const bf16x8*)(vrow + (q4 ^ r7) * 8);
#pragma unroll
      for (int rg = 0; rg < 2; rg++)
        o[rg][nt] = __builtin_amdgcn_mfma_f32_16x16x32_bf16(afrag[rg], bv, o[rg][nt], 0, 0, 0);
    }
  }

  int b = bh >> 3, h = bh & 7;
#pragma unroll
  for (int rg = 0; rg < 2; rg++) {
    float inv[4];
#pragma unroll
    for (int r = 0; r < 4; r++) {
      float l = lsum[rg][r];
      l += __shfl_xor(l, 1);
      l += __shfl_xor(l, 2);
      l += __shfl_xor(l, 4);
      l += __shfl_xor(l, 8);
      inv[r] = 1.0f / l;
    }
#pragma unroll
    for (int nt = 0; nt < 3; nt++)
#pragma unroll
      for (int r = 0; r < 4; r++) {
        int n = n0 + rg * 16 + q4 * 4 + r;
        if (n < NTOK) outb[((size_t)(b * NTOK + n)) * 384 + h * 48 + nt * 16 + c16] = f2bf(o[rg][nt][r] * inv[r]);
      }
  }
}

extern "C" void kernel_launch(void* const* d_in, const int* in_sizes, int n_in,
                              void* d_out, int out_size, void* d_ws, size_t ws_size,
                              hipStream_t stream) {
  const float* x = (const float*)d_in[0];
  const float* q_w = (const float*)d_in[1];
  const float* kv_w = (const float*)d_in[2];
  const float* proj_w = (const float*)d_in[3];
  const float* proj_b = (const float*)d_in[4];
  const float* sr_w = (const float*)d_in[5];
  const float* sr_b = (const float*)d_in[6];
  const float* ln_g = (const float*)d_in[7];
  const float* ln_b = (const float*)d_in[8];
  float* out = (float*)d_out;

  u16* ws = (u16*)d_ws;
  u16* x_b = ws;                          // region reused for attn output (x cast eliminated)
  u16* qw_b = x_b + (size_t)ROWS_X * 384; // 147,456
  u16* kvw_b = qw_b + 147456;             // 294,912
  u16* pw_b = kvw_b + 294912;             // 147,456
  u16* q_b = pw_b + 147456;               // 32*4224*64      = 8,650,752
  u16* xln_b = q_b + (size_t)32 * NPAD_Q * 64;  // 4*544*384 = 835,584
  u16* k_b = xln_b + (size_t)4 * MPAD * 384;    // 32*640*64 = 1,310,720
  u16* vt_b = k_b + (size_t)32 * KPAD * 64;     // 32*48*640 = 983,040
  u16* attn_b = x_b;  // attn output lives in the old x_b region

  // No q_b memset (pads read as 0xAA bf16 = -3e-13; harmless per R11 audit).

  pre_kernel<<<SRLN_BLOCKS + CAST_BLOCKS, 384, 0, stream>>>(x, q_w, kv_w, proj_w, sr_w, sr_b,
                                                            ln_g, ln_b, qw_b, kvw_b, pw_b, xln_b);
  gemm_qkv<<<489, 256, 0, stream>>>(x, qw_b, xln_b, kvw_b, q_b, k_b, vt_b);
  attn_kernel<<<dim3(32, 33), 256, 0, stream>>>(q_b, k_b, vt_b, attn_b);
  gemm_out<<<387, 256, 0, stream>>>(attn_b, pw_b, out, proj_b);
}